// Round 3
// baseline (235.634 us; speedup 1.0000x reference)
//
#include <hip/hip_runtime.h>

#define NB 32
#define NPRED 65536
#define NGT 64
#define BLK 256
#define SLICES 64
#define PPT 4                  // preds per thread; block covers 1024 preds
#define NCB 128                // cumulative bins of 5px
#define CBIN_SCALE 0.2f        // 1/5

#define POS_THR 0.5f
#define NEG_THR 0.4f
#define SCAT_THR 0.1f
#define EPSF 1e-6f

// ---------- exact-op helpers ----------
// Comparison-feeding arithmetic (iou) must be bit-exact vs NumPy fp32 (no FMA
// contraction, IEEE div). Sum-only terms (focal/giou weights) tolerate ulp drift.

__device__ __forceinline__ int cbin(float x) {
    int bi = (int)(x * CBIN_SCALE);         // trunc; monotone non-decreasing
    return max(0, min(NCB - 1, bi));        // clamp keeps monotone -> superset safe
}

__device__ __forceinline__ float focal_shared(float l, bool pos) {
    float e  = expf(-fabsf(l));
    float lg = log1pf(e);
    float rp = 1.f / (1.f + e);              // sigmoid(|l|)
    float p  = (l >= 0.f) ? rp : (1.f - rp); // sigmoid(l); sum-only term
    if (pos) { float q = 1.f - p; return 0.25f * q * q * ((fmaxf(l, 0.f) - l) + lg); }
    return 0.75f * p * p * (fmaxf(l, 0.f) + lg);
}

__device__ __forceinline__ float giou_term(float px1, float py1, float px2, float py2,
                                           float gx1, float gy1, float gx2, float gy2) {
    float x1 = fmaxf(px1, gx1), y1 = fmaxf(py1, gy1);
    float x2 = fminf(px2, gx2), y2 = fminf(py2, gy2);
    float dx = fmaxf(__fsub_rn(x2, x1), 0.f);
    float dy = fmaxf(__fsub_rn(y2, y1), 0.f);
    float inter = __fmul_rn(dx, dy);
    float ap = __fmul_rn(__fsub_rn(px2, px1), __fsub_rn(py2, py1));
    float ag = __fmul_rn(__fsub_rn(gx2, gx1), __fsub_rn(gy2, gy1));
    float uni = __fsub_rn(__fadd_rn(ap, ag), inter);
    float iou = __fdiv_rn(inter, fmaxf(uni, EPSF));
    float ex1 = fminf(px1, gx1), ey1 = fminf(py1, gy1);
    float ex2 = fmaxf(px2, gx2), ey2 = fmaxf(py2, gy2);
    float enc = __fmul_rn(__fsub_rn(ex2, ex1), __fsub_rn(ey2, ey1));
    float giou = __fsub_rn(iou, __fdiv_rn(__fsub_rn(enc, uni), fmaxf(enc, EPSF)));
    return __fsub_rn(1.f, giou);
}

// ---------- Fused kernel: slice compute + per-image last-block tail +
// ---------- global last-image final reduce. Single dispatch. ----------
// keysP layout: [NB][SLICES][NGT] ullong (every entry written unconditionally;
//               contiguous 512B store per block, coalesced 512B tail loads)
// partS layout: [NB][SLICES] float4 {sum_fl, sum_gt, bitcast(v|p<<16), 0}
// doneB[NB], done2: zeroed by a 256B hipMemsetAsync before this kernel.

__global__ __launch_bounds__(BLK) void passA(
    const float* __restrict__ pred, const float* __restrict__ gt,
    unsigned long long* __restrict__ keysP,
    float4* __restrict__ partS,
    float* __restrict__ cls_b, float* __restrict__ reg_b, int* __restrict__ npos_b,
    unsigned* __restrict__ doneB, unsigned* __restrict__ done2,
    float* __restrict__ out)
{
    const int b = blockIdx.y;
    const int slice = blockIdx.x;
    const int tid = threadIdx.x;
    const int lane = tid & 63;
    const int wv = tid >> 6;

    // SoA gt (65th entry = zero dummy for branchless inline slots)
    __shared__ float sgx1[NGT + 1], sgy1[NGT + 1], sgx2[NGT + 1], sgy2[NGT + 1], sgar[NGT + 1];
    __shared__ unsigned long long skey[NGT];       // 512 B
    // cumulative candidate masks: [0]=le_x1 (prefix), [1]=ge_x2 (suffix),
    //                             [2]=le_y1 (prefix), [3]=ge_y2 (suffix)
    __shared__ unsigned long long cums[4][NCB];    // 4 KiB
    __shared__ float rfl[BLK / 64], rgt[BLK / 64];
    __shared__ int rvp[BLK / 64];
    __shared__ int isTail;
    // tail-only arrays (dead during slice phase; +1.25 KiB LDS, not occupancy-limiting)
    __shared__ float4 tgt[NGT];
    __shared__ unsigned tcn[NGT];

    // ---- pred loads first: 5 aligned float4 per thread, in flight during setup ----
    const unsigned base_n = (unsigned)(slice * (BLK * PPT));
    const float4* src4 = (const float4*)(pred + (size_t)b * NPRED * 5 + (size_t)base_n * 5)
                         + (size_t)tid * 5;
    float4 q0 = src4[0], q1 = src4[1], q2 = src4[2], q3 = src4[3], q4 = src4[4];

    // ---- gt setup ----
    const float4* gtb = (const float4*)(gt + (size_t)b * NGT * 4);
    float4 gmine;
    if (tid < NGT) gmine = gtb[tid];
    // zero the 4 point arrays (512 ullong, 2 per thread)
    ((unsigned long long*)cums)[tid] = 0ULL;
    ((unsigned long long*)cums)[tid + BLK] = 0ULL;
    if (tid < NGT) {
        sgx1[tid] = gmine.x; sgy1[tid] = gmine.y;
        sgx2[tid] = gmine.z; sgy2[tid] = gmine.w;
        sgar[tid] = __fmul_rn(__fsub_rn(gmine.z, gmine.x), __fsub_rn(gmine.w, gmine.y));
        skey[tid] = 0ULL;
    } else if (tid == NGT) {
        sgx1[NGT] = 0.f; sgy1[NGT] = 0.f; sgx2[NGT] = 0.f; sgy2[NGT] = 0.f; sgar[NGT] = 0.f;
    }
    __syncthreads();

    // point inserts (wave 0 only)
    if (tid < NGT) {
        unsigned long long bit = 1ULL << tid;
        atomicOr(&cums[0][cbin(gmine.x)], bit);   // gx1 -> prefix array
        atomicOr(&cums[1][cbin(gmine.z)], bit);   // gx2 -> suffix array
        atomicOr(&cums[2][cbin(gmine.y)], bit);   // gy1 -> prefix array
        atomicOr(&cums[3][cbin(gmine.w)], bit);   // gy2 -> suffix array
    }
    __syncthreads();

    // wave-parallel cumulative OR: wave wv scans array wv (128 bins, 2/lane).
    {
        unsigned long long v0 = cums[wv][2 * lane];
        unsigned long long v1 = cums[wv][2 * lane + 1];
        unsigned long long v = v0 | v1;
        if ((wv & 1) == 0) {
            // prefix (le): inclusive scan low->high
            #pragma unroll
            for (int off = 1; off < 64; off <<= 1) {
                unsigned long long t = __shfl_up(v, off);
                if (lane >= off) v |= t;
            }
            unsigned long long prev = __shfl_up(v, 1);
            if (lane == 0) prev = 0ULL;
            cums[wv][2 * lane]     = prev | v0;
            cums[wv][2 * lane + 1] = v;
        } else {
            // suffix (ge): inclusive scan high->low
            #pragma unroll
            for (int off = 1; off < 64; off <<= 1) {
                unsigned long long t = __shfl_down(v, off);
                if (lane + off < 64) v |= t;
            }
            unsigned long long nxt = __shfl_down(v, 1);
            if (lane == 63) nxt = 0ULL;
            cums[wv][2 * lane]     = v;
            cums[wv][2 * lane + 1] = v1 | nxt;
        }
    }
    __syncthreads();

    // ---- unpack rows: thread t owns preds 4t..4t+3 (stride-5 in the 20 floats) ----
    const float cxa[PPT] = {q0.x, q1.y, q2.z, q3.w};
    const float cya[PPT] = {q0.y, q1.z, q2.w, q4.x};
    const float wa [PPT] = {q0.z, q1.w, q3.x, q4.y};
    const float ha [PPT] = {q0.w, q2.x, q3.y, q4.z};
    const float oba[PPT] = {q1.x, q2.y, q3.z, q4.w};

    float acc_fl = 0.f, acc_gt = 0.f;
    int acc_vp = 0;   // valid count | pos count<<16

    #pragma unroll
    for (int i = 0; i < PPT; ++i) {
        const float px1 = __fsub_rn(cxa[i], __fmul_rn(wa[i], 0.5f));
        const float py1 = __fsub_rn(cya[i], __fmul_rn(ha[i], 0.5f));
        const float px2 = __fadd_rn(cxa[i], __fmul_rn(wa[i], 0.5f));
        const float py2 = __fadd_rn(cya[i], __fmul_rn(ha[i], 0.5f));
        const float area_p = __fmul_rn(__fsub_rn(px2, px1), __fsub_rn(py2, py1));

        // 4-probe candidate mask (superset of true overlaps; exact gate below)
        unsigned long long m = (cums[1][cbin(px1)] & cums[0][cbin(px2)])
                             & (cums[3][cbin(py1)] & cums[2][cbin(py2)]);

        const unsigned n = base_n + (unsigned)(PPT * tid + i);
        const unsigned long long nkey = (unsigned long long)(~n);

        float best_iou = 0.f;   // zero row -> argmax 0, matches np.argmax
        int best_j = 0;

        // branchless inline-2: dummy index 64 (zero box) -> inter=0 -> no-op
        int j0 = NGT, j1 = NGT;
        if (m) { j0 = __ffsll(m) - 1; m &= m - 1; }
        if (m) { j1 = __ffsll(m) - 1; m &= m - 1; }
        {
            float ax1 = sgx1[j0], ay1 = sgy1[j0], ax2 = sgx2[j0], ay2 = sgy2[j0], aga = sgar[j0];
            float bx1 = sgx1[j1], by1 = sgy1[j1], bx2 = sgx2[j1], by2 = sgy2[j1], agb = sgar[j1];
            float x1 = fmaxf(px1, ax1), y1 = fmaxf(py1, ay1);
            float x2 = fminf(px2, ax2), y2 = fminf(py2, ay2);
            float dx = fmaxf(__fsub_rn(x2, x1), 0.f);
            float dy = fmaxf(__fsub_rn(y2, y1), 0.f);
            float inter = __fmul_rn(dx, dy);
            float uni = __fsub_rn(__fadd_rn(area_p, aga), inter);
            float iou = __fdiv_rn(inter, fmaxf(uni, EPSF));
            iou = (inter > 0.f) ? iou : 0.f;
            if (iou > best_iou) { best_iou = iou; best_j = j0; }
            if (iou > SCAT_THR)
                atomicMax(&skey[j0], (((unsigned long long)__float_as_uint(iou)) << 32) | nkey);

            float X1 = fmaxf(px1, bx1), Y1 = fmaxf(py1, by1);
            float X2 = fminf(px2, bx2), Y2 = fminf(py2, by2);
            float dX = fmaxf(__fsub_rn(X2, X1), 0.f);
            float dY = fmaxf(__fsub_rn(Y2, Y1), 0.f);
            float interB = __fmul_rn(dX, dY);
            float uniB = __fsub_rn(__fadd_rn(area_p, agb), interB);
            float iouB = __fdiv_rn(interB, fmaxf(uniB, EPSF));
            iouB = (interB > 0.f) ? iouB : 0.f;
            if (iouB > best_iou) { best_iou = iouB; best_j = j1; }
            if (iouB > SCAT_THR)
                atomicMax(&skey[j1], (((unsigned long long)__float_as_uint(iouB)) << 32) | nkey);
        }

        // rare remainder (2-way unrolled)
        while (m) {
            int ja = __ffsll(m) - 1; m &= m - 1;
            int jb = -1;
            if (m) { jb = __ffsll(m) - 1; m &= m - 1; }
            int jbc = (jb >= 0) ? jb : NGT;
            float ax1 = sgx1[ja], ay1 = sgy1[ja], ax2 = sgx2[ja], ay2 = sgy2[ja], aga = sgar[ja];
            float bx1 = sgx1[jbc], by1 = sgy1[jbc], bx2 = sgx2[jbc], by2 = sgy2[jbc], agb = sgar[jbc];
            {
                float x1 = fmaxf(px1, ax1), y1 = fmaxf(py1, ay1);
                float x2 = fminf(px2, ax2), y2 = fminf(py2, ay2);
                float dx = fmaxf(__fsub_rn(x2, x1), 0.f);
                float dy = fmaxf(__fsub_rn(y2, y1), 0.f);
                float inter = __fmul_rn(dx, dy);
                if (inter > 0.f) {
                    float uni = __fsub_rn(__fadd_rn(area_p, aga), inter);
                    float iou = __fdiv_rn(inter, fmaxf(uni, EPSF));
                    if (iou > best_iou) { best_iou = iou; best_j = ja; }
                    if (iou > SCAT_THR)
                        atomicMax(&skey[ja], (((unsigned long long)__float_as_uint(iou)) << 32) | nkey);
                }
            }
            if (jb >= 0) {
                float x1 = fmaxf(px1, bx1), y1 = fmaxf(py1, by1);
                float x2 = fminf(px2, bx2), y2 = fminf(py2, by2);
                float dx = fmaxf(__fsub_rn(x2, x1), 0.f);
                float dy = fmaxf(__fsub_rn(y2, y1), 0.f);
                float inter = __fmul_rn(dx, dy);
                if (inter > 0.f) {
                    float uni = __fsub_rn(__fadd_rn(area_p, agb), inter);
                    float iou = __fdiv_rn(inter, fmaxf(uni, EPSF));
                    if (iou > best_iou) { best_iou = iou; best_j = jb; }
                    if (iou > SCAT_THR)
                        atomicMax(&skey[jb], (((unsigned long long)__float_as_uint(iou)) << 32) | nkey);
                }
            }
        }

        const bool pos0   = best_iou > POS_THR;
        const bool negf   = best_iou < NEG_THR;
        const bool valid0 = pos0 || negf;
        if (valid0) acc_fl += focal_shared(oba[i], pos0);
        if (pos0) {
            acc_gt += giou_term(px1, py1, px2, py2,
                                sgx1[best_j], sgy1[best_j], sgx2[best_j], sgy2[best_j]);
        }
        acc_vp += (valid0 ? 1 : 0) | (pos0 ? 0x10000 : 0);
    }

    // one reduction + plain per-slice stores (no global atomics)
    for (int off = 32; off; off >>= 1) {
        acc_fl += __shfl_down(acc_fl, off);
        acc_gt += __shfl_down(acc_gt, off);
        acc_vp += __shfl_down(acc_vp, off);
    }
    if (lane == 0) { rfl[wv] = acc_fl; rgt[wv] = acc_gt; rvp[wv] = acc_vp; }
    __syncthreads();   // also orders all skey LDS atomics before the drain
    if (tid == 0) {
        float sfl = 0.f, sgt2 = 0.f; int svp = 0;
        #pragma unroll
        for (int i = 0; i < BLK / 64; ++i) { sfl += rfl[i]; sgt2 += rgt[i]; svp += rvp[i]; }
        partS[b * SLICES + slice] = make_float4(sfl, sgt2, __int_as_float(svp), 0.f);
    }
    if (tid < NGT) {
        // [b][slice][gt]: contiguous 512B per block
        keysP[((size_t)b * SLICES + slice) * NGT + tid] = skey[tid];
    }

    // ---- per-image completion: release own writes, count in ----
    __threadfence();       // every thread releases its own global stores
    __syncthreads();       // order all fences before the counting atomic
    if (tid == 0) {
        unsigned old = atomicAdd(&doneB[b], 1u);
        isTail = (old == SLICES - 1) ? 1 : 0;
    }
    __syncthreads();
    if (!isTail) return;   // uniform per block

    // =====================================================================
    // Tail for image b (exactly the verified passB code, run on wave 0).
    // All 64 producer blocks for b have released their keysP/partS writes.
    // =====================================================================
    __threadfence();       // acquire side
    if (tid < 64) {
        float4 gj = gtb[lane];
        tgt[lane] = gj;

        // per-gt key = max over 64 slices; [b][slice][gt] -> coalesced 512B loads
        const unsigned long long* kp = keysP + (size_t)b * SLICES * NGT + lane;
        unsigned long long key = 0ULL;
        #pragma unroll 16
        for (int s = 0; s < SLICES; ++s) {
            unsigned long long k = kp[(size_t)s * NGT];
            key = (k > key) ? k : key;
        }

        float miou = __uint_as_float((unsigned)(key >> 32));
        unsigned n = ~((unsigned)(key & 0xFFFFFFFFULL));
        bool qual = miou > SCAT_THR;   // key==0 -> miou=0 -> false

        // dedupe: keep first qualifying lane per pred index (ref .at[].max semantics)
        bool unique = qual;
        for (int j2 = 0; j2 < NGT; ++j2) {
            unsigned bn = __shfl(n, j2);
            int bq = __shfl((int)qual, j2);
            if (bq && j2 < lane && bn == n) unique = false;
        }
        unsigned long long mask = __ballot(unique ? 1 : 0);
        int NC = __popcll(mask);
        int slot = __popcll(mask & ((1ULL << lane) - 1ULL));
        if (unique) tcn[slot] = n;
        // wave-coherent LDS: compiler's lgkmcnt wait orders write->read in-wave

        // candidate-parallel: lane l recomputes candidate l's full best_gt argmax
        float cx = 0.f, cy = 0.f, w = 0.f, h = 0.f, obj = 0.f;
        if (lane < NC) {
            const float* p = pred + (size_t)b * NPRED * 5 + (size_t)tcn[lane] * 5;
            cx = p[0]; cy = p[1]; w = p[2]; h = p[3]; obj = p[4];
        }
        float px1 = __fsub_rn(cx, __fmul_rn(w, 0.5f));
        float py1 = __fsub_rn(cy, __fmul_rn(h, 0.5f));
        float px2 = __fadd_rn(cx, __fmul_rn(w, 0.5f));
        float py2 = __fadd_rn(cy, __fmul_rn(h, 0.5f));
        float area_p = __fmul_rn(__fsub_rn(px2, px1), __fsub_rn(py2, py1));

        float bv = 0.f; int bj = 0;
        #pragma unroll 4
        for (int j = 0; j < NGT; ++j) {
            float4 g = tgt[j];   // uniform -> broadcast
            float x1 = fmaxf(px1, g.x), y1 = fmaxf(py1, g.y);
            float x2 = fminf(px2, g.z), y2 = fminf(py2, g.w);
            float dx = fmaxf(__fsub_rn(x2, x1), 0.f);
            float dy = fmaxf(__fsub_rn(y2, y1), 0.f);
            float inter = __fmul_rn(dx, dy);
            if (inter > 0.f) {   // identical op sequence to slice phase
                float ag = __fmul_rn(__fsub_rn(g.z, g.x), __fsub_rn(g.w, g.y));
                float uni = __fsub_rn(__fadd_rn(area_p, ag), inter);
                float iou = __fdiv_rn(inter, fmaxf(uni, EPSF));
                if (iou > bv) { bv = iou; bj = j; }   // strict > == np.argmax first-max
            }
        }

        double add_fl = 0.0, add_gt = 0.0;
        int add_v = 0, add_p = 0;
        if (lane < NC && !(bv > POS_THR)) {   // slice phase counted non-pos: flip to pos
            bool was_neg = bv < NEG_THR;      // == valid0 in slice phase
            float f1 = focal_shared(obj, true);
            float f0 = focal_shared(obj, false);
            add_fl = (double)f1 - (was_neg ? (double)f0 : 0.0);
            add_v = was_neg ? 0 : 1;
            add_p = 1;
            float4 gb = tgt[bj];
            add_gt = (double)giou_term(px1, py1, px2, py2, gb.x, gb.y, gb.z, gb.w);
        }

        // per-slice partial sums for this image (lane == slice index)
        float4 ps = partS[b * SLICES + lane];
        double sfl = (double)ps.x + add_fl;
        double sgt2 = (double)ps.y + add_gt;
        int vpk = __float_as_int(ps.z);
        int sv = (vpk & 0xFFFF) + add_v;   // unpack BEFORE summing (sum exceeds 16 bits)
        int sp = (vpk >> 16) + add_p;

        for (int off = 32; off; off >>= 1) {
            sfl  += __shfl_down(sfl, off);
            sgt2 += __shfl_down(sgt2, off);
            sv   += __shfl_down(sv, off);
            sp   += __shfl_down(sp, off);
        }

        if (lane == 0) {
            cls_b[b] = (sv > 0) ? (float)(sfl / (double)(sv > 1 ? sv : 1)) : 0.f;
            reg_b[b] = (sp > 0) ? (float)(sgt2 / (double)(sp > 1 ? sp : 1)) : 0.f;
            npos_b[b] = sp;
        }

        // last-image final reduction (device-scope atomics + fences per G16)
        __threadfence();
        unsigned t = 0;
        if (lane == 0) t = atomicAdd(done2, 1u);
        t = __shfl(t, 0);
        if (t == NB - 1) {
            __threadfence();
            volatile float* vc = cls_b;
            volatile float* vr = reg_b;
            volatile int*   vn = npos_b;
            float cv = (lane < NB) ? vc[lane] : 0.f;
            float rv = (lane < NB) ? vr[lane] : 0.f;
            int   nv = (lane < NB) ? vn[lane] : 0;
            for (int off = 32; off; off >>= 1) {
                cv += __shfl_down(cv, off);
                rv += __shfl_down(rv, off);
                nv += __shfl_down(nv, off);
            }
            if (lane == 0) {
                float num_pos = fmaxf((float)nv, 1.f);
                out[0] = cv / (float)NB + 2.0f * (rv / num_pos * (float)NB);
            }
        }
    }
}

// ---------- launcher: 1 tiny memset + 1 kernel ----------

extern "C" void kernel_launch(void* const* d_in, const int* in_sizes, int n_in,
                              void* d_out, int out_size, void* d_ws, size_t ws_size,
                              hipStream_t stream) {
    const float* pred = (const float*)d_in[0];   // (32, 65536, 5) f32
    const float* gt   = (const float*)d_in[1];   // (32, 64, 4) f32
    float* out = (float*)d_out;

    char* ws = (char*)d_ws;
    unsigned long long* keysP = (unsigned long long*)(ws + 0);      // 32*64*64*8 = 1 MiB
    float4* partS = (float4*)(ws + (size_t)NB * SLICES * NGT * 8);  // 32*64*16 = 32 KiB
    char* tail = ws + (size_t)NB * SLICES * NGT * 8 + (size_t)NB * SLICES * 16;
    float* cls_b   = (float*)(tail);                                // 128 B
    float* reg_b   = (float*)(tail + 128);                          // 128 B
    int* npos_b    = (int*)(tail + 256);                            // 128 B
    unsigned* doneB = (unsigned*)(tail + 384);                      // 128 B
    unsigned* done2 = (unsigned*)(tail + 512);                      // 4 B
    // keysP/partS/cls/reg/npos are written before read within the kernel;
    // only the two counters need pre-zero: one 256B memset.

    hipMemsetAsync(tail + 384, 0, 256, stream);

    dim3 gridA(SLICES, NB);
    passA<<<gridA, BLK, 0, stream>>>(pred, gt, keysP, partS,
                                     cls_b, reg_b, npos_b, doneB, done2, out);
}

// Round 4
// 119.360 us; speedup vs baseline: 1.9741x; 1.9741x over previous
//
#include <hip/hip_runtime.h>

#define NB 32
#define NPRED 65536
#define NGT 64
#define BLK 256
#define SLICES 32
#define PPT 8                  // preds per thread; block covers 2048 preds
#define NCB 128                // cumulative bins of 5px
#define CBIN_SCALE 0.2f        // 1/5

#define POS_THR 0.5f
#define NEG_THR 0.4f
#define SCAT_THR 0.1f
#define EPSF 1e-6f

// ---------- exact-op helpers ----------
// Comparison-feeding arithmetic (iou) must be bit-exact vs NumPy fp32 (no FMA
// contraction, IEEE div). Sum-only terms (focal/giou weights) tolerate ulp drift.

__device__ __forceinline__ int cbin(float x) {
    int bi = (int)(x * CBIN_SCALE);         // trunc; monotone non-decreasing
    return max(0, min(NCB - 1, bi));        // clamp keeps monotone -> superset safe
}

__device__ __forceinline__ float focal_shared(float l, bool pos) {
    float e  = expf(-fabsf(l));
    float lg = log1pf(e);
    float rp = 1.f / (1.f + e);              // sigmoid(|l|)
    float p  = (l >= 0.f) ? rp : (1.f - rp); // sigmoid(l); sum-only term
    if (pos) { float q = 1.f - p; return 0.25f * q * q * ((fmaxf(l, 0.f) - l) + lg); }
    return 0.75f * p * p * (fmaxf(l, 0.f) + lg);
}

__device__ __forceinline__ float giou_term(float px1, float py1, float px2, float py2,
                                           float gx1, float gy1, float gx2, float gy2) {
    float x1 = fmaxf(px1, gx1), y1 = fmaxf(py1, gy1);
    float x2 = fminf(px2, gx2), y2 = fminf(py2, gy2);
    float dx = fmaxf(__fsub_rn(x2, x1), 0.f);
    float dy = fmaxf(__fsub_rn(y2, y1), 0.f);
    float inter = __fmul_rn(dx, dy);
    float ap = __fmul_rn(__fsub_rn(px2, px1), __fsub_rn(py2, py1));
    float ag = __fmul_rn(__fsub_rn(gx2, gx1), __fsub_rn(gy2, gy1));
    float uni = __fsub_rn(__fadd_rn(ap, ag), inter);
    float iou = __fdiv_rn(inter, fmaxf(uni, EPSF));
    float ex1 = fminf(px1, gx1), ey1 = fminf(py1, gy1);
    float ex2 = fmaxf(px2, gx2), ey2 = fmaxf(py2, gy2);
    float enc = __fmul_rn(__fsub_rn(ex2, ex1), __fsub_rn(ey2, ey1));
    float giou = __fsub_rn(iou, __fdiv_rn(__fsub_rn(enc, uni), fmaxf(enc, EPSF)));
    return __fsub_rn(1.f, giou);
}

// ---------- Pass A: per-slice partials, NO global atomics, NO pre-zero ----------
// keysP layout: [NB][SLICES][NGT] ullong (every entry written unconditionally;
//               contiguous 512B store per block, coalesced 512B loads in passB)
// partS layout: [NB][SLICES] float4 {sum_fl, sum_gt, bitcast(v|p<<16), 0}
// done: zeroed by block (0,0) -- stream ordering makes it visible to passB.

__global__ __launch_bounds__(BLK) void passA(
    const float* __restrict__ pred, const float* __restrict__ gt,
    unsigned long long* __restrict__ keysP,
    float4* __restrict__ partS,
    unsigned* __restrict__ done)
{
    const int b = blockIdx.y;
    const int slice = blockIdx.x;
    const int tid = threadIdx.x;
    const int lane = tid & 63;
    const int wv = tid >> 6;

    if (b == 0 && slice == 0 && tid == 0) *done = 0u;   // replaces memset dispatch

    // SoA gt (65th entry = zero dummy for branchless inline slots)
    __shared__ float sgx1[NGT + 1], sgy1[NGT + 1], sgx2[NGT + 1], sgy2[NGT + 1], sgar[NGT + 1];
    __shared__ unsigned long long skey[NGT];       // 512 B
    // cumulative candidate masks: [0]=le_x1 (prefix), [1]=ge_x2 (suffix),
    //                             [2]=le_y1 (prefix), [3]=ge_y2 (suffix)
    __shared__ unsigned long long cums[4][NCB];    // 4 KiB
    __shared__ float rfl[BLK / 64], rgt[BLK / 64];
    __shared__ int rvp[BLK / 64];

    // ---- pred loads first: 10 aligned float4 per thread, in flight during setup ----
    const unsigned base_n = (unsigned)(slice * (BLK * PPT));
    const float4* src4 = (const float4*)(pred + (size_t)b * NPRED * 5 + (size_t)base_n * 5)
                         + (size_t)tid * 10;
    float4 q0 = src4[0], q1 = src4[1], q2 = src4[2], q3 = src4[3], q4 = src4[4];
    float4 q5 = src4[5], q6 = src4[6], q7 = src4[7], q8 = src4[8], q9 = src4[9];

    // ---- gt setup ----
    const float4* gtb = (const float4*)(gt + (size_t)b * NGT * 4);
    float4 gmine;
    if (tid < NGT) gmine = gtb[tid];
    // zero the 4 point arrays (512 ullong, 2 per thread)
    ((unsigned long long*)cums)[tid] = 0ULL;
    ((unsigned long long*)cums)[tid + BLK] = 0ULL;
    if (tid < NGT) {
        sgx1[tid] = gmine.x; sgy1[tid] = gmine.y;
        sgx2[tid] = gmine.z; sgy2[tid] = gmine.w;
        sgar[tid] = __fmul_rn(__fsub_rn(gmine.z, gmine.x), __fsub_rn(gmine.w, gmine.y));
        skey[tid] = 0ULL;
    } else if (tid == NGT) {
        sgx1[NGT] = 0.f; sgy1[NGT] = 0.f; sgx2[NGT] = 0.f; sgy2[NGT] = 0.f; sgar[NGT] = 0.f;
    }
    __syncthreads();

    // point inserts (wave 0 only)
    if (tid < NGT) {
        unsigned long long bit = 1ULL << tid;
        atomicOr(&cums[0][cbin(gmine.x)], bit);   // gx1 -> prefix array
        atomicOr(&cums[1][cbin(gmine.z)], bit);   // gx2 -> suffix array
        atomicOr(&cums[2][cbin(gmine.y)], bit);   // gy1 -> prefix array
        atomicOr(&cums[3][cbin(gmine.w)], bit);   // gy2 -> suffix array
    }
    __syncthreads();

    // wave-parallel cumulative OR: wave wv scans array wv (128 bins, 2/lane).
    {
        unsigned long long v0 = cums[wv][2 * lane];
        unsigned long long v1 = cums[wv][2 * lane + 1];
        unsigned long long v = v0 | v1;
        if ((wv & 1) == 0) {
            // prefix (le): inclusive scan low->high
            #pragma unroll
            for (int off = 1; off < 64; off <<= 1) {
                unsigned long long t = __shfl_up(v, off);
                if (lane >= off) v |= t;
            }
            unsigned long long prev = __shfl_up(v, 1);
            if (lane == 0) prev = 0ULL;
            cums[wv][2 * lane]     = prev | v0;
            cums[wv][2 * lane + 1] = v;
        } else {
            // suffix (ge): inclusive scan high->low
            #pragma unroll
            for (int off = 1; off < 64; off <<= 1) {
                unsigned long long t = __shfl_down(v, off);
                if (lane + off < 64) v |= t;
            }
            unsigned long long nxt = __shfl_down(v, 1);
            if (lane == 63) nxt = 0ULL;
            cums[wv][2 * lane]     = v;
            cums[wv][2 * lane + 1] = v1 | nxt;
        }
    }
    __syncthreads();

    // ---- unpack rows: thread t owns preds 8t..8t+7 (stride-5 in the 40 floats) ----
    const float cxa[PPT] = {q0.x, q1.y, q2.z, q3.w, q5.x, q6.y, q7.z, q8.w};
    const float cya[PPT] = {q0.y, q1.z, q2.w, q4.x, q5.y, q6.z, q7.w, q9.x};
    const float wa [PPT] = {q0.z, q1.w, q3.x, q4.y, q5.z, q6.w, q8.x, q9.y};
    const float ha [PPT] = {q0.w, q2.x, q3.y, q4.z, q5.w, q7.x, q8.y, q9.z};
    const float oba[PPT] = {q1.x, q2.y, q3.z, q4.w, q6.x, q7.y, q8.z, q9.w};

    float acc_fl = 0.f, acc_gt = 0.f;
    int acc_vp = 0;   // valid count | pos count<<16

    #pragma unroll
    for (int i = 0; i < PPT; ++i) {
        const float px1 = __fsub_rn(cxa[i], __fmul_rn(wa[i], 0.5f));
        const float py1 = __fsub_rn(cya[i], __fmul_rn(ha[i], 0.5f));
        const float px2 = __fadd_rn(cxa[i], __fmul_rn(wa[i], 0.5f));
        const float py2 = __fadd_rn(cya[i], __fmul_rn(ha[i], 0.5f));
        const float area_p = __fmul_rn(__fsub_rn(px2, px1), __fsub_rn(py2, py1));

        // 4-probe candidate mask (superset of true overlaps; exact gate below)
        unsigned long long m = (cums[1][cbin(px1)] & cums[0][cbin(px2)])
                             & (cums[3][cbin(py1)] & cums[2][cbin(py2)]);

        const unsigned n = base_n + (unsigned)(PPT * tid + i);
        const unsigned long long nkey = (unsigned long long)(~n);

        float best_iou = 0.f;   // zero row -> argmax 0, matches np.argmax
        int best_j = 0;

        // branchless inline-2: dummy index 64 (zero box) -> inter=0 -> no-op
        int j0 = NGT, j1 = NGT;
        if (m) { j0 = __ffsll(m) - 1; m &= m - 1; }
        if (m) { j1 = __ffsll(m) - 1; m &= m - 1; }
        {
            float ax1 = sgx1[j0], ay1 = sgy1[j0], ax2 = sgx2[j0], ay2 = sgy2[j0], aga = sgar[j0];
            float bx1 = sgx1[j1], by1 = sgy1[j1], bx2 = sgx2[j1], by2 = sgy2[j1], agb = sgar[j1];
            float x1 = fmaxf(px1, ax1), y1 = fmaxf(py1, ay1);
            float x2 = fminf(px2, ax2), y2 = fminf(py2, ay2);
            float dx = fmaxf(__fsub_rn(x2, x1), 0.f);
            float dy = fmaxf(__fsub_rn(y2, y1), 0.f);
            float inter = __fmul_rn(dx, dy);
            float uni = __fsub_rn(__fadd_rn(area_p, aga), inter);
            float iou = __fdiv_rn(inter, fmaxf(uni, EPSF));
            iou = (inter > 0.f) ? iou : 0.f;
            if (iou > best_iou) { best_iou = iou; best_j = j0; }
            if (iou > SCAT_THR)
                atomicMax(&skey[j0], (((unsigned long long)__float_as_uint(iou)) << 32) | nkey);

            float X1 = fmaxf(px1, bx1), Y1 = fmaxf(py1, by1);
            float X2 = fminf(px2, bx2), Y2 = fminf(py2, by2);
            float dX = fmaxf(__fsub_rn(X2, X1), 0.f);
            float dY = fmaxf(__fsub_rn(Y2, Y1), 0.f);
            float interB = __fmul_rn(dX, dY);
            float uniB = __fsub_rn(__fadd_rn(area_p, agb), interB);
            float iouB = __fdiv_rn(interB, fmaxf(uniB, EPSF));
            iouB = (interB > 0.f) ? iouB : 0.f;
            if (iouB > best_iou) { best_iou = iouB; best_j = j1; }
            if (iouB > SCAT_THR)
                atomicMax(&skey[j1], (((unsigned long long)__float_as_uint(iouB)) << 32) | nkey);
        }

        // rare remainder (2-way unrolled)
        while (m) {
            int ja = __ffsll(m) - 1; m &= m - 1;
            int jb = -1;
            if (m) { jb = __ffsll(m) - 1; m &= m - 1; }
            int jbc = (jb >= 0) ? jb : NGT;
            float ax1 = sgx1[ja], ay1 = sgy1[ja], ax2 = sgx2[ja], ay2 = sgy2[ja], aga = sgar[ja];
            float bx1 = sgx1[jbc], by1 = sgy1[jbc], bx2 = sgx2[jbc], by2 = sgy2[jbc], agb = sgar[jbc];
            {
                float x1 = fmaxf(px1, ax1), y1 = fmaxf(py1, ay1);
                float x2 = fminf(px2, ax2), y2 = fminf(py2, ay2);
                float dx = fmaxf(__fsub_rn(x2, x1), 0.f);
                float dy = fmaxf(__fsub_rn(y2, y1), 0.f);
                float inter = __fmul_rn(dx, dy);
                if (inter > 0.f) {
                    float uni = __fsub_rn(__fadd_rn(area_p, aga), inter);
                    float iou = __fdiv_rn(inter, fmaxf(uni, EPSF));
                    if (iou > best_iou) { best_iou = iou; best_j = ja; }
                    if (iou > SCAT_THR)
                        atomicMax(&skey[ja], (((unsigned long long)__float_as_uint(iou)) << 32) | nkey);
                }
            }
            if (jb >= 0) {
                float x1 = fmaxf(px1, bx1), y1 = fmaxf(py1, by1);
                float x2 = fminf(px2, bx2), y2 = fminf(py2, by2);
                float dx = fmaxf(__fsub_rn(x2, x1), 0.f);
                float dy = fmaxf(__fsub_rn(y2, y1), 0.f);
                float inter = __fmul_rn(dx, dy);
                if (inter > 0.f) {
                    float uni = __fsub_rn(__fadd_rn(area_p, agb), inter);
                    float iou = __fdiv_rn(inter, fmaxf(uni, EPSF));
                    if (iou > best_iou) { best_iou = iou; best_j = jb; }
                    if (iou > SCAT_THR)
                        atomicMax(&skey[jb], (((unsigned long long)__float_as_uint(iou)) << 32) | nkey);
                }
            }
        }

        const bool pos0   = best_iou > POS_THR;
        const bool negf   = best_iou < NEG_THR;
        const bool valid0 = pos0 || negf;
        if (valid0) acc_fl += focal_shared(oba[i], pos0);
        if (pos0) {
            acc_gt += giou_term(px1, py1, px2, py2,
                                sgx1[best_j], sgy1[best_j], sgx2[best_j], sgy2[best_j]);
        }
        acc_vp += (valid0 ? 1 : 0) | (pos0 ? 0x10000 : 0);
    }

    // one reduction + plain per-slice stores (no global atomics, no pre-zeroed ws)
    for (int off = 32; off; off >>= 1) {
        acc_fl += __shfl_down(acc_fl, off);
        acc_gt += __shfl_down(acc_gt, off);
        acc_vp += __shfl_down(acc_vp, off);
    }
    if (lane == 0) { rfl[wv] = acc_fl; rgt[wv] = acc_gt; rvp[wv] = acc_vp; }
    __syncthreads();   // also orders all skey LDS atomics before the drain
    if (tid == 0) {
        float sfl = 0.f, sgt2 = 0.f; int svp = 0;
        #pragma unroll
        for (int i = 0; i < BLK / 64; ++i) { sfl += rfl[i]; sgt2 += rgt[i]; svp += rvp[i]; }
        partS[b * SLICES + slice] = make_float4(sfl, sgt2, __int_as_float(svp), 0.f);
    }
    if (tid < NGT) {
        // [b][slice][gt]: contiguous 512B per block
        keysP[((size_t)b * SLICES + slice) * NGT + tid] = skey[tid];
    }
}

// ---------- Pass B: 32 blocks (one per image), 64 lanes; scatter corrections +
// ---------- per-image scalars + last-block final reduction. No memset needed. ----------

__global__ __launch_bounds__(64) void passB(
    const float* __restrict__ pred, const float* __restrict__ gt,
    const unsigned long long* __restrict__ keysP,
    const float4* __restrict__ partS,
    float* __restrict__ cls_b, float* __restrict__ reg_b, int* __restrict__ npos_b,
    unsigned* __restrict__ done, float* __restrict__ out)
{
    const int b = blockIdx.x;
    const int lane = threadIdx.x;   // one wave; lane == gt index initially

    __shared__ float4 sgt[NGT];
    __shared__ unsigned cn_list[NGT];

    const float4* gtb = (const float4*)(gt + (size_t)b * NGT * 4);
    float4 gj = gtb[lane];
    sgt[lane] = gj;

    // per-gt key = max over 32 slices; [b][slice][gt] -> each iter is one
    // coalesced 512B wave-load
    const unsigned long long* kp = keysP + (size_t)b * SLICES * NGT + lane;
    unsigned long long key = 0ULL;
    #pragma unroll 8
    for (int s = 0; s < SLICES; ++s) {
        unsigned long long k = kp[(size_t)s * NGT];
        key = (k > key) ? k : key;
    }

    float miou = __uint_as_float((unsigned)(key >> 32));
    unsigned n = ~((unsigned)(key & 0xFFFFFFFFULL));
    bool qual = miou > SCAT_THR;   // key==0 -> miou=0 -> false

    // dedupe: keep first qualifying lane per pred index (ref .at[].max semantics)
    bool unique = qual;
    for (int j2 = 0; j2 < NGT; ++j2) {
        unsigned bn = __shfl(n, j2);
        int bq = __shfl((int)qual, j2);
        if (bq && j2 < lane && bn == n) unique = false;
    }
    unsigned long long mask = __ballot(unique ? 1 : 0);
    int NC = __popcll(mask);
    int slot = __popcll(mask & ((1ULL << lane) - 1ULL));
    if (unique) cn_list[slot] = n;
    __syncthreads();

    // candidate-parallel: lane l recomputes candidate l's full best_gt argmax
    float cx = 0.f, cy = 0.f, w = 0.f, h = 0.f, obj = 0.f;
    if (lane < NC) {
        const float* p = pred + (size_t)b * NPRED * 5 + (size_t)cn_list[lane] * 5;
        cx = p[0]; cy = p[1]; w = p[2]; h = p[3]; obj = p[4];
    }
    float px1 = __fsub_rn(cx, __fmul_rn(w, 0.5f));
    float py1 = __fsub_rn(cy, __fmul_rn(h, 0.5f));
    float px2 = __fadd_rn(cx, __fmul_rn(w, 0.5f));
    float py2 = __fadd_rn(cy, __fmul_rn(h, 0.5f));
    float area_p = __fmul_rn(__fsub_rn(px2, px1), __fsub_rn(py2, py1));

    float bv = 0.f; int bj = 0;
    #pragma unroll 4
    for (int j = 0; j < NGT; ++j) {
        float4 g = sgt[j];   // uniform -> broadcast
        float x1 = fmaxf(px1, g.x), y1 = fmaxf(py1, g.y);
        float x2 = fminf(px2, g.z), y2 = fminf(py2, g.w);
        float dx = fmaxf(__fsub_rn(x2, x1), 0.f);
        float dy = fmaxf(__fsub_rn(y2, y1), 0.f);
        float inter = __fmul_rn(dx, dy);
        if (inter > 0.f) {   // identical op sequence to passA
            float ag = __fmul_rn(__fsub_rn(g.z, g.x), __fsub_rn(g.w, g.y));
            float uni = __fsub_rn(__fadd_rn(area_p, ag), inter);
            float iou = __fdiv_rn(inter, fmaxf(uni, EPSF));
            if (iou > bv) { bv = iou; bj = j; }   // strict > == np.argmax first-max
        }
    }

    double add_fl = 0.0, add_gt = 0.0;
    int add_v = 0, add_p = 0;
    if (lane < NC && !(bv > POS_THR)) {   // passA counted non-pos: flip to pos
        bool was_neg = bv < NEG_THR;      // == valid0 in passA
        float f1 = focal_shared(obj, true);
        float f0 = focal_shared(obj, false);
        add_fl = (double)f1 - (was_neg ? (double)f0 : 0.0);
        add_v = was_neg ? 0 : 1;
        add_p = 1;
        float4 gb = sgt[bj];
        add_gt = (double)giou_term(px1, py1, px2, py2, gb.x, gb.y, gb.z, gb.w);
    }

    // per-slice partial sums for this image (lane == slice index; 32 slices)
    float4 ps = (lane < SLICES) ? partS[b * SLICES + lane]
                                : make_float4(0.f, 0.f, __int_as_float(0), 0.f);
    double sfl = (double)ps.x + add_fl;
    double sgt2 = (double)ps.y + add_gt;
    int vpk = __float_as_int(ps.z);
    int sv = (vpk & 0xFFFF) + add_v;   // unpack BEFORE summing (sum exceeds 16 bits)
    int sp = (vpk >> 16) + add_p;

    for (int off = 32; off; off >>= 1) {
        sfl  += __shfl_down(sfl, off);
        sgt2 += __shfl_down(sgt2, off);
        sv   += __shfl_down(sv, off);
        sp   += __shfl_down(sp, off);
    }

    if (lane == 0) {
        cls_b[b] = (sv > 0) ? (float)(sfl / (double)(sv > 1 ? sv : 1)) : 0.f;
        reg_b[b] = (sp > 0) ? (float)(sgt2 / (double)(sp > 1 ? sp : 1)) : 0.f;
        npos_b[b] = sp;
    }

    // last-block final reduction (device-scope atomics + fences per G16)
    __threadfence();
    unsigned t = 0;
    if (lane == 0) t = atomicAdd(done, 1u);
    t = __shfl(t, 0);
    if (t == NB - 1) {
        __threadfence();
        volatile float* vc = cls_b;
        volatile float* vr = reg_b;
        volatile int*   vn = npos_b;
        float cv = (lane < NB) ? vc[lane] : 0.f;
        float rv = (lane < NB) ? vr[lane] : 0.f;
        int   nv = (lane < NB) ? vn[lane] : 0;
        for (int off = 32; off; off >>= 1) {
            cv += __shfl_down(cv, off);
            rv += __shfl_down(rv, off);
            nv += __shfl_down(nv, off);
        }
        if (lane == 0) {
            float num_pos = fmaxf((float)nv, 1.f);
            out[0] = cv / (float)NB + 2.0f * (rv / num_pos * (float)NB);
        }
    }
}

// ---------- launcher: 2 dispatches, zero memsets ----------

extern "C" void kernel_launch(void* const* d_in, const int* in_sizes, int n_in,
                              void* d_out, int out_size, void* d_ws, size_t ws_size,
                              hipStream_t stream) {
    const float* pred = (const float*)d_in[0];   // (32, 65536, 5) f32
    const float* gt   = (const float*)d_in[1];   // (32, 64, 4) f32
    float* out = (float*)d_out;

    char* ws = (char*)d_ws;
    unsigned long long* keysP = (unsigned long long*)(ws + 0);      // 32*32*64*8 = 512 KiB
    float4* partS = (float4*)(ws + (size_t)NB * SLICES * NGT * 8);  // 32*32*16 = 16 KiB
    char* tail = ws + (size_t)NB * SLICES * NGT * 8 + (size_t)NB * SLICES * 16;
    float* cls_b   = (float*)(tail);                                // 128 B
    float* reg_b   = (float*)(tail + 128);                          // 128 B
    int* npos_b    = (int*)(tail + 256);                            // 128 B
    unsigned* done = (unsigned*)(tail + 384);                       // 4 B
    // every workspace byte used is written before it is read within one
    // iteration (done is zeroed by passA block (0,0)) -> no init dispatch,
    // poison-safe.

    dim3 gridA(SLICES, NB);
    passA<<<gridA, BLK, 0, stream>>>(pred, gt, keysP, partS, done);
    passB<<<NB, 64, 0, stream>>>(pred, gt, keysP, partS,
                                 cls_b, reg_b, npos_b, done, out);
}

// Round 5
// 119.276 us; speedup vs baseline: 1.9755x; 1.0007x over previous
//
#include <hip/hip_runtime.h>

#define NB 32
#define NPRED 65536
#define NGT 64
#define BLK 256
#define SLICES 64
#define PPT 4                  // preds per thread; block covers 1024 preds
#define NCB 128                // cumulative bins of 5px
#define CBIN_SCALE 0.2f        // 1/5

#define POS_THR 0.5f
#define NEG_THR 0.4f
#define SCAT_THR 0.1f
#define EPSF 1e-6f

// ---------- exact-op helpers ----------
// Comparison-feeding arithmetic (iou) must be bit-exact vs NumPy fp32 (no FMA
// contraction, IEEE div). Sum-only terms (focal/giou weights) tolerate ulp drift.

__device__ __forceinline__ int cbin(float x) {
    int bi = (int)(x * CBIN_SCALE);         // trunc; monotone non-decreasing
    return max(0, min(NCB - 1, bi));        // clamp keeps monotone -> superset safe
}

__device__ __forceinline__ float focal_shared(float l, bool pos) {
    float e  = expf(-fabsf(l));
    float lg = log1pf(e);
    float rp = 1.f / (1.f + e);              // sigmoid(|l|)
    float p  = (l >= 0.f) ? rp : (1.f - rp); // sigmoid(l); sum-only term
    if (pos) { float q = 1.f - p; return 0.25f * q * q * ((fmaxf(l, 0.f) - l) + lg); }
    return 0.75f * p * p * (fmaxf(l, 0.f) + lg);
}

__device__ __forceinline__ float giou_term(float px1, float py1, float px2, float py2,
                                           float gx1, float gy1, float gx2, float gy2) {
    float x1 = fmaxf(px1, gx1), y1 = fmaxf(py1, gy1);
    float x2 = fminf(px2, gx2), y2 = fminf(py2, gy2);
    float dx = fmaxf(__fsub_rn(x2, x1), 0.f);
    float dy = fmaxf(__fsub_rn(y2, y1), 0.f);
    float inter = __fmul_rn(dx, dy);
    float ap = __fmul_rn(__fsub_rn(px2, px1), __fsub_rn(py2, py1));
    float ag = __fmul_rn(__fsub_rn(gx2, gx1), __fsub_rn(gy2, gy1));
    float uni = __fsub_rn(__fadd_rn(ap, ag), inter);
    float iou = __fdiv_rn(inter, fmaxf(uni, EPSF));
    float ex1 = fminf(px1, gx1), ey1 = fminf(py1, gy1);
    float ex2 = fmaxf(px2, gx2), ey2 = fmaxf(py2, gy2);
    float enc = __fmul_rn(__fsub_rn(ex2, ex1), __fsub_rn(ey2, ey1));
    float giou = __fsub_rn(iou, __fdiv_rn(__fsub_rn(enc, uni), fmaxf(enc, EPSF)));
    return __fsub_rn(1.f, giou);
}

// ---------- Fused kernel, atomics-only cross-block handoff ----------
// All cross-block data moves via device-scope atomics (coherent at the device
// point on completion). Release = s_waitcnt vmcnt(0) (drain own ops) before the
// doneB counting atomic. NO __threadfence anywhere in the 2048-block hot path
// (R3 lesson: per-block device fences = L2-writeback storm, +140us).
// ws (memset 0 before launch, ~18KB): keys[NB][NGT] ull, S_fl/S_gt[NB] dbl,
// vcnt/pcnt[NB] int, cls_b/reg_b[NB] f32, npos_b[NB] int, doneB[NB], done2.

__global__ __launch_bounds__(BLK) void passA(
    const float* __restrict__ pred, const float* __restrict__ gt,
    unsigned long long* __restrict__ keys,
    double* __restrict__ S_fl, double* __restrict__ S_gt,
    int* __restrict__ vcnt, int* __restrict__ pcnt,
    float* __restrict__ cls_b, float* __restrict__ reg_b, int* __restrict__ npos_b,
    unsigned* __restrict__ doneB, unsigned* __restrict__ done2,
    float* __restrict__ out)
{
    const int b = blockIdx.y;
    const int slice = blockIdx.x;
    const int tid = threadIdx.x;
    const int lane = tid & 63;
    const int wv = tid >> 6;

    // SoA gt (65th entry = zero dummy for branchless inline slots)
    __shared__ float sgx1[NGT + 1], sgy1[NGT + 1], sgx2[NGT + 1], sgy2[NGT + 1], sgar[NGT + 1];
    __shared__ unsigned long long skey[NGT];       // 512 B
    // cumulative candidate masks: [0]=le_x1 (prefix), [1]=ge_x2 (suffix),
    //                             [2]=le_y1 (prefix), [3]=ge_y2 (suffix)
    __shared__ unsigned long long cums[4][NCB];    // 4 KiB
    __shared__ float rfl[BLK / 64], rgt[BLK / 64];
    __shared__ int rvp[BLK / 64];
    __shared__ int isTail;
    // tail-only (dead during slice phase)
    __shared__ float4 tgt[NGT];
    __shared__ unsigned tcn[NGT];

    // ---- pred loads first: 5 aligned float4 per thread, in flight during setup ----
    const unsigned base_n = (unsigned)(slice * (BLK * PPT));
    const float4* src4 = (const float4*)(pred + (size_t)b * NPRED * 5 + (size_t)base_n * 5)
                         + (size_t)tid * 5;
    float4 q0 = src4[0], q1 = src4[1], q2 = src4[2], q3 = src4[3], q4 = src4[4];

    // ---- gt setup ----
    const float4* gtb = (const float4*)(gt + (size_t)b * NGT * 4);
    float4 gmine;
    if (tid < NGT) gmine = gtb[tid];
    // zero the 4 point arrays (512 ullong, 2 per thread)
    ((unsigned long long*)cums)[tid] = 0ULL;
    ((unsigned long long*)cums)[tid + BLK] = 0ULL;
    if (tid < NGT) {
        sgx1[tid] = gmine.x; sgy1[tid] = gmine.y;
        sgx2[tid] = gmine.z; sgy2[tid] = gmine.w;
        sgar[tid] = __fmul_rn(__fsub_rn(gmine.z, gmine.x), __fsub_rn(gmine.w, gmine.y));
        skey[tid] = 0ULL;
    } else if (tid == NGT) {
        sgx1[NGT] = 0.f; sgy1[NGT] = 0.f; sgx2[NGT] = 0.f; sgy2[NGT] = 0.f; sgar[NGT] = 0.f;
    }
    __syncthreads();

    // point inserts (wave 0 only)
    if (tid < NGT) {
        unsigned long long bit = 1ULL << tid;
        atomicOr(&cums[0][cbin(gmine.x)], bit);   // gx1 -> prefix array
        atomicOr(&cums[1][cbin(gmine.z)], bit);   // gx2 -> suffix array
        atomicOr(&cums[2][cbin(gmine.y)], bit);   // gy1 -> prefix array
        atomicOr(&cums[3][cbin(gmine.w)], bit);   // gy2 -> suffix array
    }
    __syncthreads();

    // wave-parallel cumulative OR: wave wv scans array wv (128 bins, 2/lane).
    {
        unsigned long long v0 = cums[wv][2 * lane];
        unsigned long long v1 = cums[wv][2 * lane + 1];
        unsigned long long v = v0 | v1;
        if ((wv & 1) == 0) {
            // prefix (le): inclusive scan low->high
            #pragma unroll
            for (int off = 1; off < 64; off <<= 1) {
                unsigned long long t = __shfl_up(v, off);
                if (lane >= off) v |= t;
            }
            unsigned long long prev = __shfl_up(v, 1);
            if (lane == 0) prev = 0ULL;
            cums[wv][2 * lane]     = prev | v0;
            cums[wv][2 * lane + 1] = v;
        } else {
            // suffix (ge): inclusive scan high->low
            #pragma unroll
            for (int off = 1; off < 64; off <<= 1) {
                unsigned long long t = __shfl_down(v, off);
                if (lane + off < 64) v |= t;
            }
            unsigned long long nxt = __shfl_down(v, 1);
            if (lane == 63) nxt = 0ULL;
            cums[wv][2 * lane]     = v;
            cums[wv][2 * lane + 1] = v1 | nxt;
        }
    }
    __syncthreads();

    // ---- unpack rows: thread t owns preds 4t..4t+3 (stride-5 in the 20 floats) ----
    const float cxa[PPT] = {q0.x, q1.y, q2.z, q3.w};
    const float cya[PPT] = {q0.y, q1.z, q2.w, q4.x};
    const float wa [PPT] = {q0.z, q1.w, q3.x, q4.y};
    const float ha [PPT] = {q0.w, q2.x, q3.y, q4.z};
    const float oba[PPT] = {q1.x, q2.y, q3.z, q4.w};

    float acc_fl = 0.f, acc_gt = 0.f;
    int acc_vp = 0;   // valid count | pos count<<16

    #pragma unroll
    for (int i = 0; i < PPT; ++i) {
        const float px1 = __fsub_rn(cxa[i], __fmul_rn(wa[i], 0.5f));
        const float py1 = __fsub_rn(cya[i], __fmul_rn(ha[i], 0.5f));
        const float px2 = __fadd_rn(cxa[i], __fmul_rn(wa[i], 0.5f));
        const float py2 = __fadd_rn(cya[i], __fmul_rn(ha[i], 0.5f));
        const float area_p = __fmul_rn(__fsub_rn(px2, px1), __fsub_rn(py2, py1));

        // 4-probe candidate mask (superset of true overlaps; exact gate below)
        unsigned long long m = (cums[1][cbin(px1)] & cums[0][cbin(px2)])
                             & (cums[3][cbin(py1)] & cums[2][cbin(py2)]);

        const unsigned n = base_n + (unsigned)(PPT * tid + i);
        const unsigned long long nkey = (unsigned long long)(~n);

        float best_iou = 0.f;   // zero row -> argmax 0, matches np.argmax
        int best_j = 0;

        // branchless inline-2: dummy index 64 (zero box) -> inter=0 -> no-op
        int j0 = NGT, j1 = NGT;
        if (m) { j0 = __ffsll(m) - 1; m &= m - 1; }
        if (m) { j1 = __ffsll(m) - 1; m &= m - 1; }
        {
            float ax1 = sgx1[j0], ay1 = sgy1[j0], ax2 = sgx2[j0], ay2 = sgy2[j0], aga = sgar[j0];
            float bx1 = sgx1[j1], by1 = sgy1[j1], bx2 = sgx2[j1], by2 = sgy2[j1], agb = sgar[j1];
            float x1 = fmaxf(px1, ax1), y1 = fmaxf(py1, ay1);
            float x2 = fminf(px2, ax2), y2 = fminf(py2, ay2);
            float dx = fmaxf(__fsub_rn(x2, x1), 0.f);
            float dy = fmaxf(__fsub_rn(y2, y1), 0.f);
            float inter = __fmul_rn(dx, dy);
            float uni = __fsub_rn(__fadd_rn(area_p, aga), inter);
            float iou = __fdiv_rn(inter, fmaxf(uni, EPSF));
            iou = (inter > 0.f) ? iou : 0.f;
            if (iou > best_iou) { best_iou = iou; best_j = j0; }
            if (iou > SCAT_THR)
                atomicMax(&skey[j0], (((unsigned long long)__float_as_uint(iou)) << 32) | nkey);

            float X1 = fmaxf(px1, bx1), Y1 = fmaxf(py1, by1);
            float X2 = fminf(px2, bx2), Y2 = fminf(py2, by2);
            float dX = fmaxf(__fsub_rn(X2, X1), 0.f);
            float dY = fmaxf(__fsub_rn(Y2, Y1), 0.f);
            float interB = __fmul_rn(dX, dY);
            float uniB = __fsub_rn(__fadd_rn(area_p, agb), interB);
            float iouB = __fdiv_rn(interB, fmaxf(uniB, EPSF));
            iouB = (interB > 0.f) ? iouB : 0.f;
            if (iouB > best_iou) { best_iou = iouB; best_j = j1; }
            if (iouB > SCAT_THR)
                atomicMax(&skey[j1], (((unsigned long long)__float_as_uint(iouB)) << 32) | nkey);
        }

        // rare remainder (2-way unrolled)
        while (m) {
            int ja = __ffsll(m) - 1; m &= m - 1;
            int jb = -1;
            if (m) { jb = __ffsll(m) - 1; m &= m - 1; }
            int jbc = (jb >= 0) ? jb : NGT;
            float ax1 = sgx1[ja], ay1 = sgy1[ja], ax2 = sgx2[ja], ay2 = sgy2[ja], aga = sgar[ja];
            float bx1 = sgx1[jbc], by1 = sgy1[jbc], bx2 = sgx2[jbc], by2 = sgy2[jbc], agb = sgar[jbc];
            {
                float x1 = fmaxf(px1, ax1), y1 = fmaxf(py1, ay1);
                float x2 = fminf(px2, ax2), y2 = fminf(py2, ay2);
                float dx = fmaxf(__fsub_rn(x2, x1), 0.f);
                float dy = fmaxf(__fsub_rn(y2, y1), 0.f);
                float inter = __fmul_rn(dx, dy);
                if (inter > 0.f) {
                    float uni = __fsub_rn(__fadd_rn(area_p, aga), inter);
                    float iou = __fdiv_rn(inter, fmaxf(uni, EPSF));
                    if (iou > best_iou) { best_iou = iou; best_j = ja; }
                    if (iou > SCAT_THR)
                        atomicMax(&skey[ja], (((unsigned long long)__float_as_uint(iou)) << 32) | nkey);
                }
            }
            if (jb >= 0) {
                float x1 = fmaxf(px1, bx1), y1 = fmaxf(py1, by1);
                float x2 = fminf(px2, bx2), y2 = fminf(py2, by2);
                float dx = fmaxf(__fsub_rn(x2, x1), 0.f);
                float dy = fmaxf(__fsub_rn(y2, y1), 0.f);
                float inter = __fmul_rn(dx, dy);
                if (inter > 0.f) {
                    float uni = __fsub_rn(__fadd_rn(area_p, agb), inter);
                    float iou = __fdiv_rn(inter, fmaxf(uni, EPSF));
                    if (iou > best_iou) { best_iou = iou; best_j = jb; }
                    if (iou > SCAT_THR)
                        atomicMax(&skey[jb], (((unsigned long long)__float_as_uint(iou)) << 32) | nkey);
                }
            }
        }

        const bool pos0   = best_iou > POS_THR;
        const bool negf   = best_iou < NEG_THR;
        const bool valid0 = pos0 || negf;
        if (valid0) acc_fl += focal_shared(oba[i], pos0);
        if (pos0) {
            acc_gt += giou_term(px1, py1, px2, py2,
                                sgx1[best_j], sgy1[best_j], sgx2[best_j], sgy2[best_j]);
        }
        acc_vp += (valid0 ? 1 : 0) | (pos0 ? 0x10000 : 0);
    }

    // block reduce, then R0's verified atomic epilogue (wave 0 only issues
    // global atomics -> a single vmcnt(0) on wave 0 drains them all)
    for (int off = 32; off; off >>= 1) {
        acc_fl += __shfl_down(acc_fl, off);
        acc_gt += __shfl_down(acc_gt, off);
        acc_vp += __shfl_down(acc_vp, off);
    }
    if (lane == 0) { rfl[wv] = acc_fl; rgt[wv] = acc_gt; rvp[wv] = acc_vp; }
    __syncthreads();   // also orders all skey LDS atomics before the drain
    if (tid == 0) {
        float sfl = 0.f, sgt2 = 0.f; int svp = 0;
        #pragma unroll
        for (int i = 0; i < BLK / 64; ++i) { sfl += rfl[i]; sgt2 += rgt[i]; svp += rvp[i]; }
        atomicAdd(&S_fl[b], (double)sfl);
        atomicAdd(&S_gt[b], (double)sgt2);
        atomicAdd(&vcnt[b], svp & 0xFFFF);
        atomicAdd(&pcnt[b], svp >> 16);
    }
    if (tid < NGT) {
        unsigned long long k = skey[tid];
        if (k) atomicMax(&keys[b * NGT + tid], k);
    }
    // release: wait for wave-0's atomics to COMPLETE (device-coherent point);
    // no L2 writeback needed since all cross-block data is atomic.
    if (tid < 64) asm volatile("s_waitcnt vmcnt(0)" ::: "memory");
    if (tid == 0) {
        unsigned old = atomicAdd(&doneB[b], 1u);
        isTail = (old == SLICES - 1) ? 1 : 0;
    }
    __syncthreads();
    if (!isTail) return;   // uniform per block
    if (tid >= 64) return; // tail runs on wave 0 only

    // =====================================================================
    // Tail for image b (verified passBC logic; atomic reads for coherence).
    // All 64 producers' atomics for b completed before doneB reached 64.
    // =====================================================================
    {
        float4 gj = gtb[lane];
        tgt[lane] = gj;

        unsigned long long key = atomicMax(&keys[b * NGT + lane], 0ULL); // atomic read
        float miou = __uint_as_float((unsigned)(key >> 32));
        unsigned n = ~((unsigned)(key & 0xFFFFFFFFULL));
        bool qual = miou > SCAT_THR;   // key==0 -> miou=0 -> false

        // dedupe: keep first qualifying lane per pred index (ref .at[].max semantics)
        bool unique = qual;
        for (int j2 = 0; j2 < NGT; ++j2) {
            unsigned bn = __shfl(n, j2);
            int bq = __shfl((int)qual, j2);
            if (bq && j2 < lane && bn == n) unique = false;
        }
        unsigned long long mask = __ballot(unique ? 1 : 0);
        int NC = __popcll(mask);
        int slot = __popcll(mask & ((1ULL << lane) - 1ULL));
        if (unique) tcn[slot] = n;
        // same-wave LDS visibility: drain LDS ops, pin ordering
        asm volatile("s_waitcnt lgkmcnt(0)" ::: "memory");
        __builtin_amdgcn_sched_barrier(0);

        // candidate-parallel: lane l recomputes candidate l's full best_gt argmax
        float cx = 0.f, cy = 0.f, w = 0.f, h = 0.f, obj = 0.f;
        if (lane < NC) {
            const float* p = pred + (size_t)b * NPRED * 5 + (size_t)tcn[lane] * 5;
            cx = p[0]; cy = p[1]; w = p[2]; h = p[3]; obj = p[4];
        }
        float px1 = __fsub_rn(cx, __fmul_rn(w, 0.5f));
        float py1 = __fsub_rn(cy, __fmul_rn(h, 0.5f));
        float px2 = __fadd_rn(cx, __fmul_rn(w, 0.5f));
        float py2 = __fadd_rn(cy, __fmul_rn(h, 0.5f));
        float area_p = __fmul_rn(__fsub_rn(px2, px1), __fsub_rn(py2, py1));

        float bv = 0.f; int bj = 0;
        #pragma unroll 4
        for (int j = 0; j < NGT; ++j) {
            float4 g = tgt[j];   // uniform -> broadcast
            float x1 = fmaxf(px1, g.x), y1 = fmaxf(py1, g.y);
            float x2 = fminf(px2, g.z), y2 = fminf(py2, g.w);
            float dx = fmaxf(__fsub_rn(x2, x1), 0.f);
            float dy = fmaxf(__fsub_rn(y2, y1), 0.f);
            float inter = __fmul_rn(dx, dy);
            if (inter > 0.f) {   // identical op sequence to slice phase
                float ag = __fmul_rn(__fsub_rn(g.z, g.x), __fsub_rn(g.w, g.y));
                float uni = __fsub_rn(__fadd_rn(area_p, ag), inter);
                float iou = __fdiv_rn(inter, fmaxf(uni, EPSF));
                if (iou > bv) { bv = iou; bj = j; }   // strict > == np.argmax first-max
            }
        }

        double add_fl = 0.0, add_gt = 0.0;
        int add_v = 0, add_p = 0;
        if (lane < NC && !(bv > POS_THR)) {   // slice phase counted non-pos: flip to pos
            bool was_neg = bv < NEG_THR;      // == valid0 in slice phase
            float f1 = focal_shared(obj, true);
            float f0 = focal_shared(obj, false);
            add_fl = (double)f1 - (was_neg ? (double)f0 : 0.0);
            add_v = was_neg ? 0 : 1;
            add_p = 1;
            float4 gb = tgt[bj];
            add_gt = (double)giou_term(px1, py1, px2, py2, gb.x, gb.y, gb.z, gb.w);
        }

        for (int off = 32; off; off >>= 1) {
            add_fl += __shfl_down(add_fl, off);
            add_gt += __shfl_down(add_gt, off);
            add_v  += __shfl_down(add_v, off);
            add_p  += __shfl_down(add_p, off);
        }

        unsigned t = 0;
        if (lane == 0) {
            double sfl  = atomicAdd(&S_fl[b], 0.0) + add_fl;   // atomic reads
            double sgt2 = atomicAdd(&S_gt[b], 0.0) + add_gt;
            int sv = atomicAdd(&vcnt[b], 0) + add_v;
            int sp = atomicAdd(&pcnt[b], 0) + add_p;
            float cls = (sv > 0) ? (float)(sfl / (double)(sv > 1 ? sv : 1)) : 0.f;
            float reg = (sp > 0) ? (float)(sgt2 / (double)(sp > 1 ? sp : 1)) : 0.f;
            atomicExch(&cls_b[b], cls);
            atomicExch(&reg_b[b], reg);
            atomicExch(&npos_b[b], sp);
            asm volatile("s_waitcnt vmcnt(0)" ::: "memory");  // release before count
            t = atomicAdd(done2, 1u);
        }
        t = __shfl(t, 0);
        if (t == NB - 1) {
            float cv = (lane < NB) ? atomicAdd(&cls_b[lane], 0.f) : 0.f;
            float rv = (lane < NB) ? atomicAdd(&reg_b[lane], 0.f) : 0.f;
            int   nv = (lane < NB) ? atomicAdd(&npos_b[lane], 0) : 0;
            for (int off = 32; off; off >>= 1) {
                cv += __shfl_down(cv, off);
                rv += __shfl_down(rv, off);
                nv += __shfl_down(nv, off);
            }
            if (lane == 0) {
                float num_pos = fmaxf((float)nv, 1.f);
                out[0] = cv / (float)NB + 2.0f * (rv / num_pos * (float)NB);
            }
        }
    }
}

// ---------- launcher: 1 tiny memset (18KB) + 1 kernel ----------

extern "C" void kernel_launch(void* const* d_in, const int* in_sizes, int n_in,
                              void* d_out, int out_size, void* d_ws, size_t ws_size,
                              hipStream_t stream) {
    const float* pred = (const float*)d_in[0];   // (32, 65536, 5) f32
    const float* gt   = (const float*)d_in[1];   // (32, 64, 4) f32
    float* out = (float*)d_out;

    char* ws = (char*)d_ws;
    unsigned long long* keys = (unsigned long long*)(ws + 0);       // 16384 B
    double* S_fl    = (double*)(ws + 16384);                        // 256 B
    double* S_gt    = (double*)(ws + 16640);                        // 256 B
    int* vcnt       = (int*)(ws + 16896);                           // 128 B
    int* pcnt       = (int*)(ws + 17024);                           // 128 B
    float* cls_b    = (float*)(ws + 17152);                         // 128 B
    float* reg_b    = (float*)(ws + 17280);                         // 128 B
    int* npos_b     = (int*)(ws + 17408);                           // 128 B
    unsigned* doneB = (unsigned*)(ws + 17536);                      // 128 B
    unsigned* done2 = (unsigned*)(ws + 17664);                      // 4 B

    hipMemsetAsync(d_ws, 0, 17792, stream);

    dim3 gridA(SLICES, NB);
    passA<<<gridA, BLK, 0, stream>>>(pred, gt, keys, S_fl, S_gt, vcnt, pcnt,
                                     cls_b, reg_b, npos_b, doneB, done2, out);
}

// Round 6
// 114.803 us; speedup vs baseline: 2.0525x; 1.0390x over previous
//
#include <hip/hip_runtime.h>

#define NB 32
#define NPRED 65536
#define NGT 64
#define BLK 256
#define SLICES 64
#define PPT 4                  // preds per thread; block covers 1024 preds
#define NCB 128                // cumulative bins of 5px
#define CBIN_SCALE 0.2f        // 1/5

#define POS_THR 0.5f
#define NEG_THR 0.4f
#define SCAT_THR 0.1f
#define EPSF 1e-6f

// ---------- exact-op helpers ----------
// Comparison-feeding arithmetic (iou) must be bit-exact vs NumPy fp32 (no FMA
// contraction, IEEE div). Sum-only terms (focal/giou weights) tolerate ulp drift.

__device__ __forceinline__ int cbin(float x) {
    int bi = (int)(x * CBIN_SCALE);         // trunc; monotone non-decreasing
    return max(0, min(NCB - 1, bi));        // clamp keeps monotone -> superset safe
}

__device__ __forceinline__ float focal_shared(float l, bool pos) {
    float e  = expf(-fabsf(l));
    float lg = log1pf(e);
    float rp = 1.f / (1.f + e);              // sigmoid(|l|)
    float p  = (l >= 0.f) ? rp : (1.f - rp); // sigmoid(l); sum-only term
    if (pos) { float q = 1.f - p; return 0.25f * q * q * ((fmaxf(l, 0.f) - l) + lg); }
    return 0.75f * p * p * (fmaxf(l, 0.f) + lg);
}

__device__ __forceinline__ float giou_term(float px1, float py1, float px2, float py2,
                                           float gx1, float gy1, float gx2, float gy2) {
    float x1 = fmaxf(px1, gx1), y1 = fmaxf(py1, gy1);
    float x2 = fminf(px2, gx2), y2 = fminf(py2, gy2);
    float dx = fmaxf(__fsub_rn(x2, x1), 0.f);
    float dy = fmaxf(__fsub_rn(y2, y1), 0.f);
    float inter = __fmul_rn(dx, dy);
    float ap = __fmul_rn(__fsub_rn(px2, px1), __fsub_rn(py2, py1));
    float ag = __fmul_rn(__fsub_rn(gx2, gx1), __fsub_rn(gy2, gy1));
    float uni = __fsub_rn(__fadd_rn(ap, ag), inter);
    float iou = __fdiv_rn(inter, fmaxf(uni, EPSF));
    float ex1 = fminf(px1, gx1), ey1 = fminf(py1, gy1);
    float ex2 = fmaxf(px2, gx2), ey2 = fmaxf(py2, gy2);
    float enc = __fmul_rn(__fsub_rn(ex2, ex1), __fsub_rn(ey2, ey1));
    float giou = __fsub_rn(iou, __fdiv_rn(__fsub_rn(enc, uni), fmaxf(enc, EPSF)));
    return __fsub_rn(1.f, giou);
}

// ---------- Pass A: per-slice partials, NO global atomics, NO pre-zero ----------
// keysP layout: [NB][SLICES][NGT] ullong (every entry written unconditionally;
//               contiguous 512B store per block, coalesced 512B loads in passB)
// partS layout: [NB][SLICES] float4 {sum_fl, sum_gt, bitcast(v|p<<16), 0}
// done: zeroed by block (0,0) -- stream ordering makes it visible to passB.

__global__ __launch_bounds__(BLK) void passA(
    const float* __restrict__ pred, const float* __restrict__ gt,
    unsigned long long* __restrict__ keysP,
    float4* __restrict__ partS,
    unsigned* __restrict__ done)
{
    const int b = blockIdx.y;
    const int slice = blockIdx.x;
    const int tid = threadIdx.x;
    const int lane = tid & 63;
    const int wv = tid >> 6;

    if (b == 0 && slice == 0 && tid == 0) *done = 0u;   // replaces memset dispatch

    // SoA gt (65th entry = zero dummy for branchless inline slots)
    __shared__ float sgx1[NGT + 1], sgy1[NGT + 1], sgx2[NGT + 1], sgy2[NGT + 1], sgar[NGT + 1];
    __shared__ unsigned long long skey[NGT];       // 512 B
    // cumulative candidate masks: [0]=le_x1 (prefix), [1]=ge_x2 (suffix),
    //                             [2]=le_y1 (prefix), [3]=ge_y2 (suffix)
    __shared__ unsigned long long cums[4][NCB];    // 4 KiB
    __shared__ float rfl[BLK / 64], rgt[BLK / 64];
    __shared__ int rvp[BLK / 64];

    // ---- pred loads first: 5 aligned float4 per thread, in flight during setup ----
    const unsigned base_n = (unsigned)(slice * (BLK * PPT));
    const float4* src4 = (const float4*)(pred + (size_t)b * NPRED * 5 + (size_t)base_n * 5)
                         + (size_t)tid * 5;
    float4 q0 = src4[0], q1 = src4[1], q2 = src4[2], q3 = src4[3], q4 = src4[4];

    // ---- gt setup ----
    const float4* gtb = (const float4*)(gt + (size_t)b * NGT * 4);
    float4 gmine;
    if (tid < NGT) gmine = gtb[tid];
    // zero the 4 point arrays (512 ullong, 2 per thread)
    ((unsigned long long*)cums)[tid] = 0ULL;
    ((unsigned long long*)cums)[tid + BLK] = 0ULL;
    if (tid < NGT) {
        sgx1[tid] = gmine.x; sgy1[tid] = gmine.y;
        sgx2[tid] = gmine.z; sgy2[tid] = gmine.w;
        sgar[tid] = __fmul_rn(__fsub_rn(gmine.z, gmine.x), __fsub_rn(gmine.w, gmine.y));
        skey[tid] = 0ULL;
    } else if (tid == NGT) {
        sgx1[NGT] = 0.f; sgy1[NGT] = 0.f; sgx2[NGT] = 0.f; sgy2[NGT] = 0.f; sgar[NGT] = 0.f;
    }
    __syncthreads();

    // point inserts (wave 0 only)
    if (tid < NGT) {
        unsigned long long bit = 1ULL << tid;
        atomicOr(&cums[0][cbin(gmine.x)], bit);   // gx1 -> prefix array
        atomicOr(&cums[1][cbin(gmine.z)], bit);   // gx2 -> suffix array
        atomicOr(&cums[2][cbin(gmine.y)], bit);   // gy1 -> prefix array
        atomicOr(&cums[3][cbin(gmine.w)], bit);   // gy2 -> suffix array
    }
    __syncthreads();

    // wave-parallel cumulative OR: wave wv scans array wv (128 bins, 2/lane).
    {
        unsigned long long v0 = cums[wv][2 * lane];
        unsigned long long v1 = cums[wv][2 * lane + 1];
        unsigned long long v = v0 | v1;
        if ((wv & 1) == 0) {
            // prefix (le): inclusive scan low->high
            #pragma unroll
            for (int off = 1; off < 64; off <<= 1) {
                unsigned long long t = __shfl_up(v, off);
                if (lane >= off) v |= t;
            }
            unsigned long long prev = __shfl_up(v, 1);
            if (lane == 0) prev = 0ULL;
            cums[wv][2 * lane]     = prev | v0;
            cums[wv][2 * lane + 1] = v;
        } else {
            // suffix (ge): inclusive scan high->low
            #pragma unroll
            for (int off = 1; off < 64; off <<= 1) {
                unsigned long long t = __shfl_down(v, off);
                if (lane + off < 64) v |= t;
            }
            unsigned long long nxt = __shfl_down(v, 1);
            if (lane == 63) nxt = 0ULL;
            cums[wv][2 * lane]     = v;
            cums[wv][2 * lane + 1] = v1 | nxt;
        }
    }
    __syncthreads();

    // ---- unpack rows: thread t owns preds 4t..4t+3 (stride-5 in the 20 floats) ----
    const float cxa[PPT] = {q0.x, q1.y, q2.z, q3.w};
    const float cya[PPT] = {q0.y, q1.z, q2.w, q4.x};
    const float wa [PPT] = {q0.z, q1.w, q3.x, q4.y};
    const float ha [PPT] = {q0.w, q2.x, q3.y, q4.z};
    const float oba[PPT] = {q1.x, q2.y, q3.z, q4.w};

    float acc_fl = 0.f, acc_gt = 0.f;
    int acc_vp = 0;   // valid count | pos count<<16

    #pragma unroll
    for (int i = 0; i < PPT; ++i) {
        const float px1 = __fsub_rn(cxa[i], __fmul_rn(wa[i], 0.5f));
        const float py1 = __fsub_rn(cya[i], __fmul_rn(ha[i], 0.5f));
        const float px2 = __fadd_rn(cxa[i], __fmul_rn(wa[i], 0.5f));
        const float py2 = __fadd_rn(cya[i], __fmul_rn(ha[i], 0.5f));
        const float area_p = __fmul_rn(__fsub_rn(px2, px1), __fsub_rn(py2, py1));

        // 4-probe candidate mask (superset of true overlaps; exact gate below)
        unsigned long long m = (cums[1][cbin(px1)] & cums[0][cbin(px2)])
                             & (cums[3][cbin(py1)] & cums[2][cbin(py2)]);

        const unsigned n = base_n + (unsigned)(PPT * tid + i);
        const unsigned long long nkey = (unsigned long long)(~n);

        float best_iou = 0.f;   // zero row -> argmax 0, matches np.argmax
        int best_j = 0;

        // branchless inline-2: dummy index 64 (zero box) -> inter=0 -> no-op
        int j0 = NGT, j1 = NGT;
        if (m) { j0 = __ffsll(m) - 1; m &= m - 1; }
        if (m) { j1 = __ffsll(m) - 1; m &= m - 1; }
        {
            float ax1 = sgx1[j0], ay1 = sgy1[j0], ax2 = sgx2[j0], ay2 = sgy2[j0], aga = sgar[j0];
            float bx1 = sgx1[j1], by1 = sgy1[j1], bx2 = sgx2[j1], by2 = sgy2[j1], agb = sgar[j1];
            float x1 = fmaxf(px1, ax1), y1 = fmaxf(py1, ay1);
            float x2 = fminf(px2, ax2), y2 = fminf(py2, ay2);
            float dx = fmaxf(__fsub_rn(x2, x1), 0.f);
            float dy = fmaxf(__fsub_rn(y2, y1), 0.f);
            float inter = __fmul_rn(dx, dy);
            float uni = __fsub_rn(__fadd_rn(area_p, aga), inter);
            float iou = __fdiv_rn(inter, fmaxf(uni, EPSF));
            iou = (inter > 0.f) ? iou : 0.f;
            if (iou > best_iou) { best_iou = iou; best_j = j0; }
            if (iou > SCAT_THR)
                atomicMax(&skey[j0], (((unsigned long long)__float_as_uint(iou)) << 32) | nkey);

            float X1 = fmaxf(px1, bx1), Y1 = fmaxf(py1, by1);
            float X2 = fminf(px2, bx2), Y2 = fminf(py2, by2);
            float dX = fmaxf(__fsub_rn(X2, X1), 0.f);
            float dY = fmaxf(__fsub_rn(Y2, Y1), 0.f);
            float interB = __fmul_rn(dX, dY);
            float uniB = __fsub_rn(__fadd_rn(area_p, agb), interB);
            float iouB = __fdiv_rn(interB, fmaxf(uniB, EPSF));
            iouB = (interB > 0.f) ? iouB : 0.f;
            if (iouB > best_iou) { best_iou = iouB; best_j = j1; }
            if (iouB > SCAT_THR)
                atomicMax(&skey[j1], (((unsigned long long)__float_as_uint(iouB)) << 32) | nkey);
        }

        // rare remainder (2-way unrolled)
        while (m) {
            int ja = __ffsll(m) - 1; m &= m - 1;
            int jb = -1;
            if (m) { jb = __ffsll(m) - 1; m &= m - 1; }
            int jbc = (jb >= 0) ? jb : NGT;
            float ax1 = sgx1[ja], ay1 = sgy1[ja], ax2 = sgx2[ja], ay2 = sgy2[ja], aga = sgar[ja];
            float bx1 = sgx1[jbc], by1 = sgy1[jbc], bx2 = sgx2[jbc], by2 = sgy2[jbc], agb = sgar[jbc];
            {
                float x1 = fmaxf(px1, ax1), y1 = fmaxf(py1, ay1);
                float x2 = fminf(px2, ax2), y2 = fminf(py2, ay2);
                float dx = fmaxf(__fsub_rn(x2, x1), 0.f);
                float dy = fmaxf(__fsub_rn(y2, y1), 0.f);
                float inter = __fmul_rn(dx, dy);
                if (inter > 0.f) {
                    float uni = __fsub_rn(__fadd_rn(area_p, aga), inter);
                    float iou = __fdiv_rn(inter, fmaxf(uni, EPSF));
                    if (iou > best_iou) { best_iou = iou; best_j = ja; }
                    if (iou > SCAT_THR)
                        atomicMax(&skey[ja], (((unsigned long long)__float_as_uint(iou)) << 32) | nkey);
                }
            }
            if (jb >= 0) {
                float x1 = fmaxf(px1, bx1), y1 = fmaxf(py1, by1);
                float x2 = fminf(px2, bx2), y2 = fminf(py2, by2);
                float dx = fmaxf(__fsub_rn(x2, x1), 0.f);
                float dy = fmaxf(__fsub_rn(y2, y1), 0.f);
                float inter = __fmul_rn(dx, dy);
                if (inter > 0.f) {
                    float uni = __fsub_rn(__fadd_rn(area_p, agb), inter);
                    float iou = __fdiv_rn(inter, fmaxf(uni, EPSF));
                    if (iou > best_iou) { best_iou = iou; best_j = jb; }
                    if (iou > SCAT_THR)
                        atomicMax(&skey[jb], (((unsigned long long)__float_as_uint(iou)) << 32) | nkey);
                }
            }
        }

        const bool pos0   = best_iou > POS_THR;
        const bool negf   = best_iou < NEG_THR;
        const bool valid0 = pos0 || negf;
        if (valid0) acc_fl += focal_shared(oba[i], pos0);
        if (pos0) {
            acc_gt += giou_term(px1, py1, px2, py2,
                                sgx1[best_j], sgy1[best_j], sgx2[best_j], sgy2[best_j]);
        }
        acc_vp += (valid0 ? 1 : 0) | (pos0 ? 0x10000 : 0);
    }

    // one reduction + plain per-slice stores (no global atomics, no pre-zeroed ws)
    for (int off = 32; off; off >>= 1) {
        acc_fl += __shfl_down(acc_fl, off);
        acc_gt += __shfl_down(acc_gt, off);
        acc_vp += __shfl_down(acc_vp, off);
    }
    if (lane == 0) { rfl[wv] = acc_fl; rgt[wv] = acc_gt; rvp[wv] = acc_vp; }
    __syncthreads();   // also orders all skey LDS atomics before the drain
    if (tid == 0) {
        float sfl = 0.f, sgt2 = 0.f; int svp = 0;
        #pragma unroll
        for (int i = 0; i < BLK / 64; ++i) { sfl += rfl[i]; sgt2 += rgt[i]; svp += rvp[i]; }
        partS[b * SLICES + slice] = make_float4(sfl, sgt2, __int_as_float(svp), 0.f);
    }
    if (tid < NGT) {
        // [b][slice][gt]: contiguous 512B per block
        keysP[((size_t)b * SLICES + slice) * NGT + tid] = skey[tid];
    }
}

// ---------- Pass B: 32 blocks (one per image), 64 lanes; scatter corrections +
// ---------- per-image scalars + last-block final reduction. No memset needed. ----------

__global__ __launch_bounds__(64) void passB(
    const float* __restrict__ pred, const float* __restrict__ gt,
    const unsigned long long* __restrict__ keysP,
    const float4* __restrict__ partS,
    float* __restrict__ cls_b, float* __restrict__ reg_b, int* __restrict__ npos_b,
    unsigned* __restrict__ done, float* __restrict__ out)
{
    const int b = blockIdx.x;
    const int lane = threadIdx.x;   // one wave; lane == gt index initially

    __shared__ float4 sgt[NGT];
    __shared__ unsigned cn_list[NGT];

    const float4* gtb = (const float4*)(gt + (size_t)b * NGT * 4);
    float4 gj = gtb[lane];
    sgt[lane] = gj;

    // per-gt key = max over 64 slices; [b][slice][gt] -> each iter is one
    // coalesced 512B wave-load
    const unsigned long long* kp = keysP + (size_t)b * SLICES * NGT + lane;
    unsigned long long key = 0ULL;
    #pragma unroll 16
    for (int s = 0; s < SLICES; ++s) {
        unsigned long long k = kp[(size_t)s * NGT];
        key = (k > key) ? k : key;
    }

    float miou = __uint_as_float((unsigned)(key >> 32));
    unsigned n = ~((unsigned)(key & 0xFFFFFFFFULL));
    bool qual = miou > SCAT_THR;   // key==0 -> miou=0 -> false

    // dedupe: keep first qualifying lane per pred index (ref .at[].max semantics)
    bool unique = qual;
    for (int j2 = 0; j2 < NGT; ++j2) {
        unsigned bn = __shfl(n, j2);
        int bq = __shfl((int)qual, j2);
        if (bq && j2 < lane && bn == n) unique = false;
    }
    unsigned long long mask = __ballot(unique ? 1 : 0);
    int NC = __popcll(mask);
    int slot = __popcll(mask & ((1ULL << lane) - 1ULL));
    if (unique) cn_list[slot] = n;
    __syncthreads();

    // candidate-parallel: lane l recomputes candidate l's full best_gt argmax
    float cx = 0.f, cy = 0.f, w = 0.f, h = 0.f, obj = 0.f;
    if (lane < NC) {
        const float* p = pred + (size_t)b * NPRED * 5 + (size_t)cn_list[lane] * 5;
        cx = p[0]; cy = p[1]; w = p[2]; h = p[3]; obj = p[4];
    }
    float px1 = __fsub_rn(cx, __fmul_rn(w, 0.5f));
    float py1 = __fsub_rn(cy, __fmul_rn(h, 0.5f));
    float px2 = __fadd_rn(cx, __fmul_rn(w, 0.5f));
    float py2 = __fadd_rn(cy, __fmul_rn(h, 0.5f));
    float area_p = __fmul_rn(__fsub_rn(px2, px1), __fsub_rn(py2, py1));

    float bv = 0.f; int bj = 0;
    #pragma unroll 4
    for (int j = 0; j < NGT; ++j) {
        float4 g = sgt[j];   // uniform -> broadcast
        float x1 = fmaxf(px1, g.x), y1 = fmaxf(py1, g.y);
        float x2 = fminf(px2, g.z), y2 = fminf(py2, g.w);
        float dx = fmaxf(__fsub_rn(x2, x1), 0.f);
        float dy = fmaxf(__fsub_rn(y2, y1), 0.f);
        float inter = __fmul_rn(dx, dy);
        if (inter > 0.f) {   // identical op sequence to passA
            float ag = __fmul_rn(__fsub_rn(g.z, g.x), __fsub_rn(g.w, g.y));
            float uni = __fsub_rn(__fadd_rn(area_p, ag), inter);
            float iou = __fdiv_rn(inter, fmaxf(uni, EPSF));
            if (iou > bv) { bv = iou; bj = j; }   // strict > == np.argmax first-max
        }
    }

    double add_fl = 0.0, add_gt = 0.0;
    int add_v = 0, add_p = 0;
    if (lane < NC && !(bv > POS_THR)) {   // passA counted non-pos: flip to pos
        bool was_neg = bv < NEG_THR;      // == valid0 in passA
        float f1 = focal_shared(obj, true);
        float f0 = focal_shared(obj, false);
        add_fl = (double)f1 - (was_neg ? (double)f0 : 0.0);
        add_v = was_neg ? 0 : 1;
        add_p = 1;
        float4 gb = sgt[bj];
        add_gt = (double)giou_term(px1, py1, px2, py2, gb.x, gb.y, gb.z, gb.w);
    }

    // per-slice partial sums for this image (lane == slice index)
    float4 ps = partS[b * SLICES + lane];
    double sfl = (double)ps.x + add_fl;
    double sgt2 = (double)ps.y + add_gt;
    int vpk = __float_as_int(ps.z);
    int sv = (vpk & 0xFFFF) + add_v;   // unpack BEFORE summing (sum exceeds 16 bits)
    int sp = (vpk >> 16) + add_p;

    for (int off = 32; off; off >>= 1) {
        sfl  += __shfl_down(sfl, off);
        sgt2 += __shfl_down(sgt2, off);
        sv   += __shfl_down(sv, off);
        sp   += __shfl_down(sp, off);
    }

    if (lane == 0) {
        cls_b[b] = (sv > 0) ? (float)(sfl / (double)(sv > 1 ? sv : 1)) : 0.f;
        reg_b[b] = (sp > 0) ? (float)(sgt2 / (double)(sp > 1 ? sp : 1)) : 0.f;
        npos_b[b] = sp;
    }

    // last-block final reduction (device-scope atomics + fences per G16)
    __threadfence();
    unsigned t = 0;
    if (lane == 0) t = atomicAdd(done, 1u);
    t = __shfl(t, 0);
    if (t == NB - 1) {
        __threadfence();
        volatile float* vc = cls_b;
        volatile float* vr = reg_b;
        volatile int*   vn = npos_b;
        float cv = (lane < NB) ? vc[lane] : 0.f;
        float rv = (lane < NB) ? vr[lane] : 0.f;
        int   nv = (lane < NB) ? vn[lane] : 0;
        for (int off = 32; off; off >>= 1) {
            cv += __shfl_down(cv, off);
            rv += __shfl_down(rv, off);
            nv += __shfl_down(nv, off);
        }
        if (lane == 0) {
            float num_pos = fmaxf((float)nv, 1.f);
            out[0] = cv / (float)NB + 2.0f * (rv / num_pos * (float)NB);
        }
    }
}

// ---------- launcher: 2 dispatches, zero memsets ----------

extern "C" void kernel_launch(void* const* d_in, const int* in_sizes, int n_in,
                              void* d_out, int out_size, void* d_ws, size_t ws_size,
                              hipStream_t stream) {
    const float* pred = (const float*)d_in[0];   // (32, 65536, 5) f32
    const float* gt   = (const float*)d_in[1];   // (32, 64, 4) f32
    float* out = (float*)d_out;

    char* ws = (char*)d_ws;
    unsigned long long* keysP = (unsigned long long*)(ws + 0);      // 32*64*64*8 = 1 MiB
    float4* partS = (float4*)(ws + (size_t)NB * SLICES * NGT * 8);  // 32*64*16 = 32 KiB
    char* tail = ws + (size_t)NB * SLICES * NGT * 8 + (size_t)NB * SLICES * 16;
    float* cls_b   = (float*)(tail);                                // 128 B
    float* reg_b   = (float*)(tail + 128);                          // 128 B
    int* npos_b    = (int*)(tail + 256);                            // 128 B
    unsigned* done = (unsigned*)(tail + 384);                       // 4 B
    // every workspace byte used is written before it is read within one
    // iteration (done is zeroed by passA block (0,0)) -> no init dispatch,
    // poison-safe.

    dim3 gridA(SLICES, NB);
    passA<<<gridA, BLK, 0, stream>>>(pred, gt, keysP, partS, done);
    passB<<<NB, 64, 0, stream>>>(pred, gt, keysP, partS,
                                 cls_b, reg_b, npos_b, done, out);
}

// Round 8
// 113.523 us; speedup vs baseline: 2.0756x; 1.0113x over previous
//
#include <hip/hip_runtime.h>

#define NB 32
#define NPRED 65536
#define NGT 64
#define BLK 256
#define SLICES 64
#define PPT 4                  // preds per thread; block covers 1024 preds
#define NCB 128                // cumulative bins of 5px
#define CBIN_SCALE 0.2f        // 1/5

#define POS_THR 0.5f
#define NEG_THR 0.4f
#define SCAT_THR 0.1f
#define EPSF 1e-6f

typedef float f32x4 __attribute__((ext_vector_type(4)));

// ---------- exact-op helpers ----------
// Comparison-feeding arithmetic (iou) must be bit-exact vs NumPy fp32 (no FMA
// contraction, IEEE div). Sum-only terms (focal/giou weights) tolerate ulp drift.

__device__ __forceinline__ int cbin(float x) {
    int bi = (int)(x * CBIN_SCALE);         // trunc; monotone non-decreasing
    return max(0, min(NCB - 1, bi));        // clamp keeps monotone -> superset safe
}

__device__ __forceinline__ float focal_shared(float l, bool pos) {
    float e  = expf(-fabsf(l));
    float lg = log1pf(e);
    float rp = 1.f / (1.f + e);              // sigmoid(|l|)
    float p  = (l >= 0.f) ? rp : (1.f - rp); // sigmoid(l); sum-only term
    if (pos) { float q = 1.f - p; return 0.25f * q * q * ((fmaxf(l, 0.f) - l) + lg); }
    return 0.75f * p * p * (fmaxf(l, 0.f) + lg);
}

__device__ __forceinline__ float giou_term(float px1, float py1, float px2, float py2,
                                           float gx1, float gy1, float gx2, float gy2) {
    float x1 = fmaxf(px1, gx1), y1 = fmaxf(py1, gy1);
    float x2 = fminf(px2, gx2), y2 = fminf(py2, gy2);
    float dx = fmaxf(__fsub_rn(x2, x1), 0.f);
    float dy = fmaxf(__fsub_rn(y2, y1), 0.f);
    float inter = __fmul_rn(dx, dy);
    float ap = __fmul_rn(__fsub_rn(px2, px1), __fsub_rn(py2, py1));
    float ag = __fmul_rn(__fsub_rn(gx2, gx1), __fsub_rn(gy2, gy1));
    float uni = __fsub_rn(__fadd_rn(ap, ag), inter);
    float iou = __fdiv_rn(inter, fmaxf(uni, EPSF));
    float ex1 = fminf(px1, gx1), ey1 = fminf(py1, gy1);
    float ex2 = fmaxf(px2, gx2), ey2 = fmaxf(py2, gy2);
    float enc = __fmul_rn(__fsub_rn(ex2, ex1), __fsub_rn(ey2, ey1));
    float giou = __fsub_rn(iou, __fdiv_rn(__fsub_rn(enc, uni), fmaxf(enc, EPSF)));
    return __fsub_rn(1.f, giou);
}

// ---------- Pass A: per-slice partials, NO global atomics, NO pre-zero ----------
// keysP layout: [NB][SLICES][NGT] ullong (every entry written unconditionally;
//               contiguous 512B store per block, coalesced 512B loads in passB)
// partS layout: [NB][SLICES] float4 {sum_fl, sum_gt, bitcast(v|p<<16), 0}
// done: zeroed by block (0,0) -- stream ordering makes it visible to passB.
//
// Load scheduling: pred/gt loads are issued via asm volatile global_load so the
// compiler can NOT sink or rematerialize them (observed: VGPR_Count=24 -> it
// was deferring the 20-reg pred block past the prologue, serializing HBM
// latency behind the gt/scan setup). gt issues first; vmcnt(5) releases it for
// the prologue while the 5 pred loads stay in flight across the LDS build +
// scan. CRITICAL (R7 lesson): the waitcnt pass does NOT track inline-asm loads
// -- an explicit s_waitcnt vmcnt(0) + sched_barrier is required before the
// first use of q0..q4 (the implicit barrier waitcnt does NOT cover them).

__global__ __launch_bounds__(BLK) void passA(
    const float* __restrict__ pred, const float* __restrict__ gt,
    unsigned long long* __restrict__ keysP,
    float4* __restrict__ partS,
    unsigned* __restrict__ done)
{
    const int b = blockIdx.y;
    const int slice = blockIdx.x;
    const int tid = threadIdx.x;
    const int lane = tid & 63;
    const int wv = tid >> 6;

    if (b == 0 && slice == 0 && tid == 0) *done = 0u;   // replaces memset dispatch

    // gt boxes packed: one ds_read_b128 per candidate probe (bank-conflict fix)
    __shared__ float4 sgbox[NGT + 1];              // 65th = zero dummy
    __shared__ float sgar[NGT + 1];
    __shared__ unsigned long long skey[NGT];       // 512 B
    // cumulative candidate masks: [0]=le_x1 (prefix), [1]=ge_x2 (suffix),
    //                             [2]=le_y1 (prefix), [3]=ge_y2 (suffix)
    __shared__ unsigned long long cums[4][NCB];    // 4 KiB
    __shared__ float rfl[BLK / 64], rgt[BLK / 64];
    __shared__ int rvp[BLK / 64];

    // ---- forced-early loads: gt first, then 5 pred float4 per thread ----
    const unsigned base_n = (unsigned)(slice * (BLK * PPT));
    const float4* gtb = (const float4*)(gt + (size_t)b * NGT * 4);
    const float* gaddr = (const float*)(gtb + (tid & 63));          // clamped in-bounds
    const float* paddr = (const float*)((const float4*)(pred + (size_t)b * NPRED * 5
                                        + (size_t)base_n * 5) + (size_t)tid * 5);
    f32x4 gq, q0, q1, q2, q3, q4;
    asm volatile("global_load_dwordx4 %0, %1, off"           : "=v"(gq) : "v"(gaddr));
    asm volatile("global_load_dwordx4 %0, %1, off"           : "=v"(q0) : "v"(paddr));
    asm volatile("global_load_dwordx4 %0, %1, off offset:16" : "=v"(q1) : "v"(paddr));
    asm volatile("global_load_dwordx4 %0, %1, off offset:32" : "=v"(q2) : "v"(paddr));
    asm volatile("global_load_dwordx4 %0, %1, off offset:48" : "=v"(q3) : "v"(paddr));
    asm volatile("global_load_dwordx4 %0, %1, off offset:64" : "=v"(q4) : "v"(paddr));
    asm volatile("s_waitcnt vmcnt(5)" ::: "memory");   // gt ready; preds in flight
    __builtin_amdgcn_sched_barrier(0);                 // rule #18: fence the wait

    // ---- gt setup (pred loads still in flight underneath) ----
    // zero the 4 point arrays (512 ullong, 2 per thread)
    ((unsigned long long*)cums)[tid] = 0ULL;
    ((unsigned long long*)cums)[tid + BLK] = 0ULL;
    if (tid < NGT) {
        sgbox[tid] = make_float4(gq[0], gq[1], gq[2], gq[3]);
        sgar[tid] = __fmul_rn(__fsub_rn(gq[2], gq[0]), __fsub_rn(gq[3], gq[1]));
        skey[tid] = 0ULL;
    } else if (tid == NGT) {
        sgbox[NGT] = make_float4(0.f, 0.f, 0.f, 0.f);
        sgar[NGT] = 0.f;
    }
    __syncthreads();

    // point inserts (wave 0 only)
    if (tid < NGT) {
        unsigned long long bit = 1ULL << tid;
        atomicOr(&cums[0][cbin(gq[0])], bit);   // gx1 -> prefix array
        atomicOr(&cums[1][cbin(gq[2])], bit);   // gx2 -> suffix array
        atomicOr(&cums[2][cbin(gq[1])], bit);   // gy1 -> prefix array
        atomicOr(&cums[3][cbin(gq[3])], bit);   // gy2 -> suffix array
    }
    __syncthreads();

    // wave-parallel cumulative OR: wave wv scans array wv (128 bins, 2/lane).
    {
        unsigned long long v0 = cums[wv][2 * lane];
        unsigned long long v1 = cums[wv][2 * lane + 1];
        unsigned long long v = v0 | v1;
        if ((wv & 1) == 0) {
            // prefix (le): inclusive scan low->high
            #pragma unroll
            for (int off = 1; off < 64; off <<= 1) {
                unsigned long long t = __shfl_up(v, off);
                if (lane >= off) v |= t;
            }
            unsigned long long prev = __shfl_up(v, 1);
            if (lane == 0) prev = 0ULL;
            cums[wv][2 * lane]     = prev | v0;
            cums[wv][2 * lane + 1] = v;
        } else {
            // suffix (ge): inclusive scan high->low
            #pragma unroll
            for (int off = 1; off < 64; off <<= 1) {
                unsigned long long t = __shfl_down(v, off);
                if (lane + off < 64) v |= t;
            }
            unsigned long long nxt = __shfl_down(v, 1);
            if (lane == 63) nxt = 0ULL;
            cums[wv][2 * lane]     = v;
            cums[wv][2 * lane + 1] = v1 | nxt;
        }
    }
    __syncthreads();

    // R7 fix: drain the 5 inline-asm pred loads BEFORE first use -- the
    // compiler's waitcnt pass cannot see them, so no implicit wait exists.
    asm volatile("s_waitcnt vmcnt(0)" ::: "memory");
    __builtin_amdgcn_sched_barrier(0);

    // ---- unpack rows: thread t owns preds 4t..4t+3 (stride-5 in the 20 floats) ----
    const float cxa[PPT] = {q0[0], q1[1], q2[2], q3[3]};
    const float cya[PPT] = {q0[1], q1[2], q2[3], q4[0]};
    const float wa [PPT] = {q0[2], q1[3], q3[0], q4[1]};
    const float ha [PPT] = {q0[3], q2[0], q3[1], q4[2]};
    const float oba[PPT] = {q1[0], q2[1], q3[2], q4[3]};

    float acc_fl = 0.f, acc_gt = 0.f;
    int acc_vp = 0;   // valid count | pos count<<16

    #pragma unroll
    for (int i = 0; i < PPT; ++i) {
        const float px1 = __fsub_rn(cxa[i], __fmul_rn(wa[i], 0.5f));
        const float py1 = __fsub_rn(cya[i], __fmul_rn(ha[i], 0.5f));
        const float px2 = __fadd_rn(cxa[i], __fmul_rn(wa[i], 0.5f));
        const float py2 = __fadd_rn(cya[i], __fmul_rn(ha[i], 0.5f));
        const float area_p = __fmul_rn(__fsub_rn(px2, px1), __fsub_rn(py2, py1));

        // 4-probe candidate mask (superset of true overlaps; exact gate below)
        unsigned long long m = (cums[1][cbin(px1)] & cums[0][cbin(px2)])
                             & (cums[3][cbin(py1)] & cums[2][cbin(py2)]);

        const unsigned n = base_n + (unsigned)(PPT * tid + i);
        const unsigned long long nkey = (unsigned long long)(~n);

        float best_iou = 0.f;   // zero row -> argmax 0, matches np.argmax
        int best_j = 0;

        // branchless inline-2: dummy index 64 (zero box) -> inter=0 -> no-op
        int j0 = NGT, j1 = NGT;
        if (m) { j0 = __ffsll(m) - 1; m &= m - 1; }
        if (m) { j1 = __ffsll(m) - 1; m &= m - 1; }
        {
            float4 ga = sgbox[j0]; float aga = sgar[j0];
            float4 gbx = sgbox[j1]; float agb = sgar[j1];
            float x1 = fmaxf(px1, ga.x), y1 = fmaxf(py1, ga.y);
            float x2 = fminf(px2, ga.z), y2 = fminf(py2, ga.w);
            float dx = fmaxf(__fsub_rn(x2, x1), 0.f);
            float dy = fmaxf(__fsub_rn(y2, y1), 0.f);
            float inter = __fmul_rn(dx, dy);
            float uni = __fsub_rn(__fadd_rn(area_p, aga), inter);
            float iou = __fdiv_rn(inter, fmaxf(uni, EPSF));
            iou = (inter > 0.f) ? iou : 0.f;
            if (iou > best_iou) { best_iou = iou; best_j = j0; }
            if (iou > SCAT_THR)
                atomicMax(&skey[j0], (((unsigned long long)__float_as_uint(iou)) << 32) | nkey);

            float X1 = fmaxf(px1, gbx.x), Y1 = fmaxf(py1, gbx.y);
            float X2 = fminf(px2, gbx.z), Y2 = fminf(py2, gbx.w);
            float dX = fmaxf(__fsub_rn(X2, X1), 0.f);
            float dY = fmaxf(__fsub_rn(Y2, Y1), 0.f);
            float interB = __fmul_rn(dX, dY);
            float uniB = __fsub_rn(__fadd_rn(area_p, agb), interB);
            float iouB = __fdiv_rn(interB, fmaxf(uniB, EPSF));
            iouB = (interB > 0.f) ? iouB : 0.f;
            if (iouB > best_iou) { best_iou = iouB; best_j = j1; }
            if (iouB > SCAT_THR)
                atomicMax(&skey[j1], (((unsigned long long)__float_as_uint(iouB)) << 32) | nkey);
        }

        // rare remainder (2-way unrolled)
        while (m) {
            int ja = __ffsll(m) - 1; m &= m - 1;
            int jb = -1;
            if (m) { jb = __ffsll(m) - 1; m &= m - 1; }
            int jbc = (jb >= 0) ? jb : NGT;
            float4 ga = sgbox[ja]; float aga = sgar[ja];
            float4 gbx = sgbox[jbc]; float agb = sgar[jbc];
            {
                float x1 = fmaxf(px1, ga.x), y1 = fmaxf(py1, ga.y);
                float x2 = fminf(px2, ga.z), y2 = fminf(py2, ga.w);
                float dx = fmaxf(__fsub_rn(x2, x1), 0.f);
                float dy = fmaxf(__fsub_rn(y2, y1), 0.f);
                float inter = __fmul_rn(dx, dy);
                if (inter > 0.f) {
                    float uni = __fsub_rn(__fadd_rn(area_p, aga), inter);
                    float iou = __fdiv_rn(inter, fmaxf(uni, EPSF));
                    if (iou > best_iou) { best_iou = iou; best_j = ja; }
                    if (iou > SCAT_THR)
                        atomicMax(&skey[ja], (((unsigned long long)__float_as_uint(iou)) << 32) | nkey);
                }
            }
            if (jb >= 0) {
                float x1 = fmaxf(px1, gbx.x), y1 = fmaxf(py1, gbx.y);
                float x2 = fminf(px2, gbx.z), y2 = fminf(py2, gbx.w);
                float dx = fmaxf(__fsub_rn(x2, x1), 0.f);
                float dy = fmaxf(__fsub_rn(y2, y1), 0.f);
                float inter = __fmul_rn(dx, dy);
                if (inter > 0.f) {
                    float uni = __fsub_rn(__fadd_rn(area_p, agb), inter);
                    float iou = __fdiv_rn(inter, fmaxf(uni, EPSF));
                    if (iou > best_iou) { best_iou = iou; best_j = jb; }
                    if (iou > SCAT_THR)
                        atomicMax(&skey[jb], (((unsigned long long)__float_as_uint(iou)) << 32) | nkey);
                }
            }
        }

        const bool pos0   = best_iou > POS_THR;
        const bool negf   = best_iou < NEG_THR;
        const bool valid0 = pos0 || negf;
        if (valid0) acc_fl += focal_shared(oba[i], pos0);
        if (pos0) {
            float4 gbb = sgbox[best_j];
            acc_gt += giou_term(px1, py1, px2, py2, gbb.x, gbb.y, gbb.z, gbb.w);
        }
        acc_vp += (valid0 ? 1 : 0) | (pos0 ? 0x10000 : 0);
    }

    // one reduction + plain per-slice stores (no global atomics, no pre-zeroed ws)
    for (int off = 32; off; off >>= 1) {
        acc_fl += __shfl_down(acc_fl, off);
        acc_gt += __shfl_down(acc_gt, off);
        acc_vp += __shfl_down(acc_vp, off);
    }
    if (lane == 0) { rfl[wv] = acc_fl; rgt[wv] = acc_gt; rvp[wv] = acc_vp; }
    __syncthreads();   // also orders all skey LDS atomics before the drain
    if (tid == 0) {
        float sfl = 0.f, sgt2 = 0.f; int svp = 0;
        #pragma unroll
        for (int i = 0; i < BLK / 64; ++i) { sfl += rfl[i]; sgt2 += rgt[i]; svp += rvp[i]; }
        partS[b * SLICES + slice] = make_float4(sfl, sgt2, __int_as_float(svp), 0.f);
    }
    if (tid < NGT) {
        // [b][slice][gt]: contiguous 512B per block
        keysP[((size_t)b * SLICES + slice) * NGT + tid] = skey[tid];
    }
}

// ---------- Pass B: 32 blocks (one per image), 64 lanes; scatter corrections +
// ---------- per-image scalars + last-block final reduction. No memset needed. ----------

__global__ __launch_bounds__(64) void passB(
    const float* __restrict__ pred, const float* __restrict__ gt,
    const unsigned long long* __restrict__ keysP,
    const float4* __restrict__ partS,
    float* __restrict__ cls_b, float* __restrict__ reg_b, int* __restrict__ npos_b,
    unsigned* __restrict__ done, float* __restrict__ out)
{
    const int b = blockIdx.x;
    const int lane = threadIdx.x;   // one wave; lane == gt index initially

    __shared__ float4 sgt[NGT];
    __shared__ unsigned cn_list[NGT];

    const float4* gtb = (const float4*)(gt + (size_t)b * NGT * 4);
    float4 gj = gtb[lane];
    sgt[lane] = gj;

    // per-gt key = max over 64 slices; [b][slice][gt] -> each iter is one
    // coalesced 512B wave-load
    const unsigned long long* kp = keysP + (size_t)b * SLICES * NGT + lane;
    unsigned long long key = 0ULL;
    #pragma unroll 16
    for (int s = 0; s < SLICES; ++s) {
        unsigned long long k = kp[(size_t)s * NGT];
        key = (k > key) ? k : key;
    }

    float miou = __uint_as_float((unsigned)(key >> 32));
    unsigned n = ~((unsigned)(key & 0xFFFFFFFFULL));
    bool qual = miou > SCAT_THR;   // key==0 -> miou=0 -> false

    // dedupe: keep first qualifying lane per pred index (ref .at[].max semantics)
    bool unique = qual;
    for (int j2 = 0; j2 < NGT; ++j2) {
        unsigned bn = __shfl(n, j2);
        int bq = __shfl((int)qual, j2);
        if (bq && j2 < lane && bn == n) unique = false;
    }
    unsigned long long mask = __ballot(unique ? 1 : 0);
    int NC = __popcll(mask);
    int slot = __popcll(mask & ((1ULL << lane) - 1ULL));
    if (unique) cn_list[slot] = n;
    __syncthreads();

    // candidate-parallel: lane l recomputes candidate l's full best_gt argmax
    float cx = 0.f, cy = 0.f, w = 0.f, h = 0.f, obj = 0.f;
    if (lane < NC) {
        const float* p = pred + (size_t)b * NPRED * 5 + (size_t)cn_list[lane] * 5;
        cx = p[0]; cy = p[1]; w = p[2]; h = p[3]; obj = p[4];
    }
    float px1 = __fsub_rn(cx, __fmul_rn(w, 0.5f));
    float py1 = __fsub_rn(cy, __fmul_rn(h, 0.5f));
    float px2 = __fadd_rn(cx, __fmul_rn(w, 0.5f));
    float py2 = __fadd_rn(cy, __fmul_rn(h, 0.5f));
    float area_p = __fmul_rn(__fsub_rn(px2, px1), __fsub_rn(py2, py1));

    float bv = 0.f; int bj = 0;
    #pragma unroll 4
    for (int j = 0; j < NGT; ++j) {
        float4 g = sgt[j];   // uniform -> broadcast
        float x1 = fmaxf(px1, g.x), y1 = fmaxf(py1, g.y);
        float x2 = fminf(px2, g.z), y2 = fminf(py2, g.w);
        float dx = fmaxf(__fsub_rn(x2, x1), 0.f);
        float dy = fmaxf(__fsub_rn(y2, y1), 0.f);
        float inter = __fmul_rn(dx, dy);
        if (inter > 0.f) {   // identical op sequence to passA
            float ag = __fmul_rn(__fsub_rn(g.z, g.x), __fsub_rn(g.w, g.y));
            float uni = __fsub_rn(__fadd_rn(area_p, ag), inter);
            float iou = __fdiv_rn(inter, fmaxf(uni, EPSF));
            if (iou > bv) { bv = iou; bj = j; }   // strict > == np.argmax first-max
        }
    }

    double add_fl = 0.0, add_gt = 0.0;
    int add_v = 0, add_p = 0;
    if (lane < NC && !(bv > POS_THR)) {   // passA counted non-pos: flip to pos
        bool was_neg = bv < NEG_THR;      // == valid0 in passA
        float f1 = focal_shared(obj, true);
        float f0 = focal_shared(obj, false);
        add_fl = (double)f1 - (was_neg ? (double)f0 : 0.0);
        add_v = was_neg ? 0 : 1;
        add_p = 1;
        float4 gb = sgt[bj];
        add_gt = (double)giou_term(px1, py1, px2, py2, gb.x, gb.y, gb.z, gb.w);
    }

    // per-slice partial sums for this image (lane == slice index)
    float4 ps = partS[b * SLICES + lane];
    double sfl = (double)ps.x + add_fl;
    double sgt2 = (double)ps.y + add_gt;
    int vpk = __float_as_int(ps.z);
    int sv = (vpk & 0xFFFF) + add_v;   // unpack BEFORE summing (sum exceeds 16 bits)
    int sp = (vpk >> 16) + add_p;

    for (int off = 32; off; off >>= 1) {
        sfl  += __shfl_down(sfl, off);
        sgt2 += __shfl_down(sgt2, off);
        sv   += __shfl_down(sv, off);
        sp   += __shfl_down(sp, off);
    }

    if (lane == 0) {
        cls_b[b] = (sv > 0) ? (float)(sfl / (double)(sv > 1 ? sv : 1)) : 0.f;
        reg_b[b] = (sp > 0) ? (float)(sgt2 / (double)(sp > 1 ? sp : 1)) : 0.f;
        npos_b[b] = sp;
    }

    // last-block final reduction (device-scope atomics + fences per G16)
    __threadfence();
    unsigned t = 0;
    if (lane == 0) t = atomicAdd(done, 1u);
    t = __shfl(t, 0);
    if (t == NB - 1) {
        __threadfence();
        volatile float* vc = cls_b;
        volatile float* vr = reg_b;
        volatile int*   vn = npos_b;
        float cv = (lane < NB) ? vc[lane] : 0.f;
        float rv = (lane < NB) ? vr[lane] : 0.f;
        int   nv = (lane < NB) ? vn[lane] : 0;
        for (int off = 32; off; off >>= 1) {
            cv += __shfl_down(cv, off);
            rv += __shfl_down(rv, off);
            nv += __shfl_down(nv, off);
        }
        if (lane == 0) {
            float num_pos = fmaxf((float)nv, 1.f);
            out[0] = cv / (float)NB + 2.0f * (rv / num_pos * (float)NB);
        }
    }
}

// ---------- launcher: 2 dispatches, zero memsets ----------

extern "C" void kernel_launch(void* const* d_in, const int* in_sizes, int n_in,
                              void* d_out, int out_size, void* d_ws, size_t ws_size,
                              hipStream_t stream) {
    const float* pred = (const float*)d_in[0];   // (32, 65536, 5) f32
    const float* gt   = (const float*)d_in[1];   // (32, 64, 4) f32
    float* out = (float*)d_out;

    char* ws = (char*)d_ws;
    unsigned long long* keysP = (unsigned long long*)(ws + 0);      // 32*64*64*8 = 1 MiB
    float4* partS = (float4*)(ws + (size_t)NB * SLICES * NGT * 8);  // 32*64*16 = 32 KiB
    char* tail = ws + (size_t)NB * SLICES * NGT * 8 + (size_t)NB * SLICES * 16;
    float* cls_b   = (float*)(tail);                                // 128 B
    float* reg_b   = (float*)(tail + 128);                          // 128 B
    int* npos_b    = (int*)(tail + 256);                            // 128 B
    unsigned* done = (unsigned*)(tail + 384);                       // 4 B
    // every workspace byte used is written before it is read within one
    // iteration (done is zeroed by passA block (0,0)) -> no init dispatch,
    // poison-safe.

    dim3 gridA(SLICES, NB);
    passA<<<gridA, BLK, 0, stream>>>(pred, gt, keysP, partS, done);
    passB<<<NB, 64, 0, stream>>>(pred, gt, keysP, partS,
                                 cls_b, reg_b, npos_b, done, out);
}